// Round 14
// baseline (1597.217 us; speedup 1.0000x reference)
//
#include <hip/hip_runtime.h>
#include <hip/hip_bf16.h>
#include <cmath>

typedef __hip_bfloat16 bf16;
typedef unsigned short ushort_t;
typedef __attribute__((ext_vector_type(8))) short short8;
typedef __attribute__((ext_vector_type(4))) float floatx4;
typedef __attribute__((ext_vector_type(4))) double f64x4;
#define DEV static __device__ __forceinline__

DEV float bf2f(bf16 x) { return __bfloat162float(x); }
DEV bf16  f2bf(float x) { return __float2bfloat16(x); }

constexpr int B_  = 64, N_ = 197, C_ = 768, H_ = 12, HD_ = 64;
constexpr int C3_ = 3 * C_;      // 2304
constexpr int C4_ = 4 * C_;      // 3072
constexpr int M_  = B_ * N_;     // 12608
constexpr int BH_ = B_ * H_;     // 768
constexpr int NM1 = N_ - 1;      // 196
constexpr int KP_ = 224;         // padded attn row stride (7 x 32)

DEV ushort_t bfbits(bf16 b) { union { bf16 b; ushort_t u; } cv; cv.b = b; return cv.u; }
DEV void split_bf(float x, ushort_t& h, ushort_t& l) {
    bf16 bh = f2bf(x);
    float fh = bf2f(bh);
    bf16 bl = f2bf(x - fh);
    h = bfbits(bh); l = bfbits(bl);
}

// XCD-chunked bijective swizzle (m204)
DEV void xcd_decode(int g, int total, int nbx, int& bx, int& by) {
    const int q = total >> 3, r = total & 7;
    const int k = g & 7, s = g >> 3;
    const int w = (k < r) ? k * (q + 1) + s : r * (q + 1) + (k - r) * q + s;
    by = w / nbx; bx = w - by * nbx;
}

// wave-level f64/f32 butterfly sums (all lanes end with total)
DEV double wred64(double v) {
#pragma unroll
    for (int off = 32; off > 0; off >>= 1) v += __shfl_xor(v, off, 64);
    return v;
}
DEV float wred32(float v) {
#pragma unroll
    for (int off = 32; off > 0; off >>= 1) v += __shfl_xor(v, off, 64);
    return v;
}

// ================= f64 MFMA layout machinery =================
DEV void lay_a(int ia, int l, int& r, int& k) {
    if (ia == 0) { r = l & 15; k = l >> 4; }
    else         { r = l >> 2; k = l & 3;  }
}
DEV void lay_b(int ib, int l, int& k, int& c) {
    if (ib == 0) { k = l >> 4; c = l & 15; }
    else         { k = l & 3;  c = l >> 2; }
}
DEV void lay_d(int id, int l, int d, int& r, int& c) {
    int g = l >> 4, m = l & 15;
    switch (id) {
        case 0:  r = g * 4 + d; c = m; break;
        case 1:  r = g + 4 * d; c = m; break;
        case 2:  r = m; c = g * 4 + d; break;
        default: r = m; c = g + 4 * d; break;
    }
}
DEV int at_val(int i, int k) { return 1 + ((5 * i + 13 * k + 7 * i * k) % 29); }
DEV int bt_val(int k, int j) { return 1 + ((7 * j + 11 * k + 3 * j * k) % 23); }

// hardware-verified-at-runtime f64 MFMA layout probe (exact integer check)
DEV void probe_body(int l, int* mode) {
    int best = -1, nbest = 0;
    for (int ia = 0; ia < 2; ++ia) {
        for (int ib = 0; ib < 2; ++ib) {
            int ar, ak, bk, bc;
            lay_a(ia, l, ar, ak);
            lay_b(ib, l, bk, bc);
            double av = (double)at_val(ar, ak);
            double bv = (double)bt_val(bk, bc);
            f64x4 dd = {0.0, 0.0, 0.0, 0.0};
            dd = __builtin_amdgcn_mfma_f64_16x16x4f64(av, bv, dd, 0, 0, 0);
            for (int id = 0; id < 4; ++id) {
                int ok = 1;
                for (int d = 0; d < 4; ++d) {
                    int rr, cc; lay_d(id, l, d, rr, cc);
                    double ref = 0.0;
                    for (int k = 0; k < 4; ++k)
                        ref += (double)(at_val(rr, k) * bt_val(k, cc));
                    if (dd[d] != ref) ok = 0;
                }
                if (__all(ok)) { best = ia * 8 + ib * 4 + id; ++nbest; }
            }
        }
    }
    if (l == 0) *mode = (nbest == 1) ? (16 + best) : 0;
}

// ---------------- dtype detection ----------------
__global__ __launch_bounds__(256) void detect_kernel(const ushort_t* __restrict__ w,
                                                     int* __restrict__ flag) {
    __shared__ int cnt;
    if (threadIdx.x == 0) cnt = 0;
    __syncthreads();
    int c = 0;
#pragma unroll
    for (int k = 0; k < 8; ++k) {
        ushort_t u = w[threadIdx.x * 8 + k];
        int e = (u >> 7) & 0xFF;
        if (e >= 143) ++c;
    }
    atomicAdd(&cnt, c);
    __syncthreads();
    if (threadIdx.x == 0) *flag = (cnt >= 8) ? 1 : 0;   // 1 = fp32 inputs
}

DEV float load_in(const void* p, size_t i, bool f32) {
    return f32 ? ((const float*)p)[i] : bf2f(((const bf16*)p)[i]);
}

// ---------------- converters ----------------
__global__ __launch_bounds__(256) void cvt64_kernel(const void* __restrict__ s, double* __restrict__ d,
                                                    int n, const int* __restrict__ flag) {
    const bool f32 = (*flag != 0);
    int i = blockIdx.x * 256 + threadIdx.x, st = gridDim.x * 256;
    for (; i < n; i += st) d[i] = (double)load_in(s, i, f32);
}

// fused small conversions + vnorm2 zero + f64-MFMA probe (bid 130)
struct PrepArgs {
    const void *bproj_s, *g1_s, *b1_s, *g2_s, *b2_s, *bfc1_s, *bfc2_s, *pol_s;
    float *bproj_d, *g2_d, *b2_d, *bfc1_d, *bfc2_d;
    double *g1_d, *b1_d, *pol_d, *vn_d;
    int* mode;
    const int* flag;
};
__global__ __launch_bounds__(256) void prep_small(PrepArgs a) {
    const bool f32 = (*a.flag != 0);
    const int bid = blockIdx.x, tid = threadIdx.x;
    if (bid < 3)       { int i = bid * 256 + tid;        a.bproj_d[i] = load_in(a.bproj_s, i, f32); }
    else if (bid < 6)  { int i = (bid - 3) * 256 + tid;  a.g1_d[i] = (double)load_in(a.g1_s, i, f32); }
    else if (bid < 9)  { int i = (bid - 6) * 256 + tid;  a.b1_d[i] = (double)load_in(a.b1_s, i, f32); }
    else if (bid < 12) { int i = (bid - 9) * 256 + tid;  a.g2_d[i] = load_in(a.g2_s, i, f32); }
    else if (bid < 15) { int i = (bid - 12) * 256 + tid; a.b2_d[i] = load_in(a.b2_s, i, f32); }
    else if (bid < 18) { int i = (bid - 15) * 256 + tid; a.bfc2_d[i] = load_in(a.bfc2_s, i, f32); }
    else if (bid < 30) { int i = (bid - 18) * 256 + tid; a.bfc1_d[i] = load_in(a.bfc1_s, i, f32); }
    else if (bid < 80) { int i = (bid - 30) * 256 + tid; if (i < M_) a.pol_d[i] = (double)load_in(a.pol_s, i, f32); }
    else if (bid < 130){ int i = (bid - 80) * 256 + tid; if (i < M_) a.vn_d[i] = 0.0; }
    else               { if (tid < 64) probe_body(tid, a.mode); }
}

// ---------------- merged weight transpose + split (4 segments, 1 launch) ----------------
struct TSArgs {
    const void *w0, *w1, *w2, *w3;
    ushort_t *h0, *l0, *h1, *l1, *h2, *l2, *h3, *l3;
    const int* flag;
};
__global__ __launch_bounds__(256) void tsplit_all(TSArgs a) {
    __shared__ float t[32][33];
    const bool f32 = (*a.flag != 0);
    const int tid = threadIdx.x;
    int bid = blockIdx.x;
    const void* W; ushort_t *hi; ushort_t *lo; int K, Nstride, nbx;
    if (bid < 1152)      {              W = a.w0; hi = a.h0; lo = a.l0; K = C_;  Nstride = C3_; nbx = 48; }
    else if (bid < 1728) { bid -= 1152; W = a.w1; hi = a.h1; lo = a.l1; K = C_;  Nstride = C_;  nbx = 24; }
    else if (bid < 4032) { bid -= 1728; W = a.w2; hi = a.h2; lo = a.l2; K = C_;  Nstride = C4_; nbx = 96; }
    else                 { bid -= 4032; W = a.w3; hi = a.h3; lo = a.l3; K = C4_; Nstride = C_;  nbx = 24; }
    const int n0 = (bid % nbx) * 32, k0 = (bid / nbx) * 32;
    for (int idx = tid; idx < 1024; idx += 256) {
        int kk = idx >> 5, nn = idx & 31;
        t[kk][nn] = load_in(W, (size_t)(k0 + kk) * Nstride + n0 + nn, f32);
    }
    __syncthreads();
    for (int idx = tid; idx < 1024; idx += 256) {
        int nn = idx >> 5, kk = idx & 31;
        ushort_t h, l; split_bf(t[kk][nn], h, l);
        size_t o = (size_t)(n0 + nn) * K + k0 + kk;
        hi[o] = h; lo[o] = l;
    }
}

// ---------------- block reductions (kept for sample) ----------------
DEV double bred_sum64(double v, double* red) {
    int t = threadIdx.x; red[t] = v; __syncthreads();
    for (int s = 128; s > 0; s >>= 1) { if (t < s) red[t] += red[t + s]; __syncthreads(); }
    double r = red[0]; __syncthreads(); return r;
}
DEV double bred_min64(double v, double* red) {
    int t = threadIdx.x; red[t] = v; __syncthreads();
    for (int s = 128; s > 0; s >>= 1) { if (t < s) red[t] = fmin(red[t], red[t + s]); __syncthreads(); }
    double r = red[0]; __syncthreads(); return r;
}

// ---------------- LN1 fp64 (wave-shfl reduction): raw x -> xn64 + xn hi/lo ----------------
__global__ __launch_bounds__(256) void ln64_kernel(const void* __restrict__ in,
                                                   const double* __restrict__ g,
                                                   const double* __restrict__ bb,
                                                   double* __restrict__ out,
                                                   ushort_t* __restrict__ oh,
                                                   ushort_t* __restrict__ ol,
                                                   const int* __restrict__ flag) {
    __shared__ double part[4];
    __shared__ double part2[4];
    const bool f32 = (*flag != 0);
    const int tid = threadIdx.x, lane = tid & 63, w = tid >> 6;
    const size_t row = blockIdx.x;
    double x0 = (double)load_in(in, row * C_ + tid, f32);
    double x1 = (double)load_in(in, row * C_ + tid + 256, f32);
    double x2 = (double)load_in(in, row * C_ + tid + 512, f32);
    double s = wred64(x0 + x1 + x2);
    if (lane == 0) part[w] = s;
    __syncthreads();
    double m = (part[0] + part[1] + part[2] + part[3]) / 768.0;
    double d0 = x0 - m, d1 = x1 - m, d2 = x2 - m;
    double vv = wred64(d0 * d0 + d1 * d1 + d2 * d2);
    if (lane == 0) part2[w] = vv;
    __syncthreads();
    double var = (part2[0] + part2[1] + part2[2] + part2[3]) / 768.0;
    double istd = 1.0 / sqrt(var + 1e-5);
    double* op = out + row * C_;
    double v0 = (d0 * istd) * g[tid]     + bb[tid];
    double v1 = (d1 * istd) * g[tid+256] + bb[tid+256];
    double v2 = (d2 * istd) * g[tid+512] + bb[tid+512];
    op[tid] = v0; op[tid+256] = v1; op[tid+512] = v2;
    ushort_t h, l;
    split_bf((float)v0, h, l); oh[row*C_+tid]     = h; ol[row*C_+tid]     = l;
    split_bf((float)v1, h, l); oh[row*C_+tid+256] = h; ol[row*C_+tid+256] = l;
    split_bf((float)v2, h, l); oh[row*C_+tid+512] = h; ol[row*C_+tid+512] = l;
}

// ---------------- LN2 fp32 (wave-shfl reduction) -> h1 hi/lo ----------------
__global__ __launch_bounds__(256) void ln32_kernel(const float* __restrict__ in,
                                                   const float* __restrict__ g,
                                                   const float* __restrict__ bb,
                                                   ushort_t* __restrict__ oh,
                                                   ushort_t* __restrict__ ol) {
    __shared__ float part[4];
    __shared__ float part2[4];
    const int tid = threadIdx.x, lane = tid & 63, w = tid >> 6;
    const size_t row = blockIdx.x;
    const float* xp = in + row * C_;
    float x0 = xp[tid], x1 = xp[tid + 256], x2 = xp[tid + 512];
    float s = wred32(x0 + x1 + x2);
    if (lane == 0) part[w] = s;
    __syncthreads();
    float m = (part[0] + part[1] + part[2] + part[3]) * (1.0f / 768.0f);
    float d0 = x0 - m, d1 = x1 - m, d2 = x2 - m;
    float vv = wred32(d0 * d0 + d1 * d1 + d2 * d2);
    if (lane == 0) part2[w] = vv;
    __syncthreads();
    float var = (part2[0] + part2[1] + part2[2] + part2[3]) * (1.0f / 768.0f);
    float istd = 1.0f / sqrtf(var + 1e-5f);
    ushort_t h, l;
    split_bf(d0 * istd * g[tid]     + bb[tid],     h, l); oh[row*C_+tid]     = h; ol[row*C_+tid]     = l;
    split_bf(d1 * istd * g[tid+256] + bb[tid+256], h, l); oh[row*C_+tid+256] = h; ol[row*C_+tid+256] = l;
    split_bf(d2 * istd * g[tid+512] + bb[tid+512], h, l); oh[row*C_+tid+512] = h; ol[row*C_+tid+512] = l;
}

// ---------------- q0 / wq0 / cls (decision path; grid-reshaped, arithmetic identical) ----------------
__global__ __launch_bounds__(256) void q0_kernel(const double* __restrict__ xn64,
                                                 const double* __restrict__ w64,
                                                 const double* __restrict__ pol,
                                                 double* __restrict__ q0) {
    const int b = blockIdx.x;
    const int j = blockIdx.y * 256 + threadIdx.x;
    const double* xr = xn64 + (size_t)(b * N_) * C_;
    double p0 = pol[b * N_];
    double acc = 0.0;
    for (int c = 0; c < C_; ++c) acc += xr[c] * w64[(size_t)c * C3_ + j];
    q0[(size_t)b * C_ + j] = acc * p0;
}

__global__ __launch_bounds__(256) void wq0_kernel(const double* __restrict__ w64,
                                                  const double* __restrict__ q0,
                                                  double* __restrict__ wq0) {
    const int b = blockIdx.x, tid = threadIdx.x;
    const int base = blockIdx.y * 3072, lim = base + 3072;
    for (int idx = base + tid; idx < lim; idx += 256) {
        int h = idx / C_, c = idx - h * C_;
        const double* wr = w64 + (size_t)c * C3_ + C_ + h * HD_;
        const double* qr = q0 + (size_t)b * C_ + h * HD_;
        double acc = 0.0;
#pragma unroll 8
        for (int d = 0; d < HD_; ++d) acc += wr[d] * qr[d];
        wq0[((size_t)b * H_ + h) * C_ + c] = acc;
    }
}

__global__ __launch_bounds__(256) void cls_kernel(const double* __restrict__ xn64,
                                                  const double* __restrict__ wq0,
                                                  const double* __restrict__ pol,
                                                  double* __restrict__ cls) {
    __shared__ double wsh[6][768];
    __shared__ double sarr[6][200];
    const int b = blockIdx.x;
    const int ph = blockIdx.y;
    const int tid = threadIdx.x, w = tid >> 6, lane = tid & 63;
    for (int idx = tid; idx < 6 * 768; idx += 256) {
        int h = idx / 768, c = idx - h * 768;
        wsh[h][c] = wq0[((size_t)b * H_ + ph * 6 + h) * C_ + c];
    }
    __syncthreads();
    for (int t = w; t < N_; t += 4) {
        const double* xr = xn64 + (size_t)(b * N_ + t) * C_;
        double xreg[12];
#pragma unroll
        for (int ch = 0; ch < 12; ++ch) xreg[ch] = xr[ch * 64 + lane];
        double pm = pol[b * N_ + t] * 0.125;
        for (int h = 0; h < 6; ++h) {
            double acc = 0.0;
#pragma unroll
            for (int ch = 0; ch < 12; ++ch) acc += xreg[ch] * wsh[h][ch * 64 + lane];
            for (int off = 32; off > 0; off >>= 1) acc += __shfl_down(acc, off, 64);
            if (lane == 0) sarr[h][t] = acc * pm;
        }
    }
    __syncthreads();
    for (int hh = w; hh < 6; hh += 4) {
        const int j0 = lane, j1 = lane + 64, j2 = lane + 128, j3 = lane + 192;
        const bool h3 = (lane < 5);
        double s0 = sarr[hh][j0], s1 = sarr[hh][j1], s2 = sarr[hh][j2];
        double s3 = h3 ? sarr[hh][j3] : -INFINITY;
        double m = fmax(fmax(s0, s2), fmax(s1, s3));
        for (int off = 32; off > 0; off >>= 1) m = fmax(m, __shfl_down(m, off, 64));
        double mx = __shfl(m, 0, 64);
        double p0 = pol[b * N_ + j0], p1 = pol[b * N_ + j1], p2 = pol[b * N_ + j2];
        double e0 = exp(s0 - mx) * (p0 + (1.0 - p0));
        if (j0 != 0) e0 = exp(s0 - mx) * p0;
        double e1 = exp(s1 - mx) * p1;
        double e2 = exp(s2 - mx) * p2;
        double e3 = 0.0;
        if (h3) { double p3 = pol[b * N_ + j3]; e3 = exp(s3 - mx) * p3; }
        double su = (e0 + e2) + (e1 + e3);
        for (int off = 32; off > 0; off >>= 1) su += __shfl_down(su, off, 64);
        double ssum = __shfl(su, 0, 64);
        double* crow = cls + ((size_t)b * H_ + ph * 6 + hh) * N_;
        crow[j0] = (e0 + 1e-6 / 197.0) / (ssum + 1e-6);
        crow[j1] = (e1 + 1e-6 / 197.0) / (ssum + 1e-6);
        crow[j2] = (e2 + 1e-6 / 197.0) / (ssum + 1e-6);
        if (h3) crow[j3] = (e3 + 1e-6 / 197.0) / (ssum + 1e-6);
    }
}

// ---------------- V GEMM v2 (round-8 proven): 64x64 tile, dual path ----------------
__global__ __launch_bounds__(256) void gemm64v2(const double* __restrict__ A,
                                                const double* __restrict__ W,
                                                const double* __restrict__ pol,
                                                float* __restrict__ v32,
                                                double* __restrict__ vnorm2,
                                                const int* __restrict__ modep) {
    __shared__ double sA[64 * 17 + 8];   // MFMA: [row][17] ; VALU view: [16][65]
    __shared__ double sB[16 * 68];       // [k][68] both paths
    __shared__ double s2buf[64];
    const int mode = *modep;
    const int tid = threadIdx.x;
    int bx, by;
    xcd_decode(blockIdx.x, 12 * 197, 12, bx, by);
    const int row0 = by * 64, col0 = bx * 64;

    if (mode >= 16) {
        // ---------- f64 MFMA path (register-prefetched) ----------
        const int lane = tid & 63, w = tid >> 6;
        const int wr = w >> 1, wc = w & 1;
        const int cb = mode - 16, ia = cb >> 3, ib = (cb >> 2) & 1, idm = cb & 3;
        int ar_f, ak_f, bk_f, bc_f;
        lay_a(ia, lane, ar_f, ak_f);
        lay_b(ib, lane, bk_f, bc_f);
        int drr[4], dcc[4];
#pragma unroll
        for (int d = 0; d < 4; ++d) lay_d(idm, lane, d, drr[d], dcc[d]);

        f64x4 acc[2][2];
#pragma unroll
        for (int i = 0; i < 2; ++i)
#pragma unroll
            for (int j = 0; j < 2; ++j) acc[i][j] = f64x4{0.0, 0.0, 0.0, 0.0};

        const int arow = tid >> 2, akk = (tid & 3) * 4;
        const int bk2 = tid >> 4, bc2 = (tid & 15) * 4;
        const double* aptr = A + (size_t)(row0 + arow) * C_ + akk;
        const double* bptr = W + (size_t)bk2 * C3_ + 2 * C_ + col0 + bc2;

        double a0 = aptr[0], a1 = aptr[1], a2 = aptr[2], a3 = aptr[3];
        double b0 = bptr[0], b1 = bptr[1], b2 = bptr[2], b3 = bptr[3];

        for (int k0 = 0; k0 < C_; k0 += 16) {
            __syncthreads();
            sA[arow * 17 + akk + 0] = a0; sA[arow * 17 + akk + 1] = a1;
            sA[arow * 17 + akk + 2] = a2; sA[arow * 17 + akk + 3] = a3;
            sB[bk2 * 68 + bc2 + 0] = b0; sB[bk2 * 68 + bc2 + 1] = b1;
            sB[bk2 * 68 + bc2 + 2] = b2; sB[bk2 * 68 + bc2 + 3] = b3;
            __syncthreads();
            if (k0 + 16 < C_) {
                const double* ap = aptr + k0 + 16;
                a0 = ap[0]; a1 = ap[1]; a2 = ap[2]; a3 = ap[3];
                const double* bp = bptr + (size_t)(k0 + 16) * C3_;
                b0 = bp[0]; b1 = bp[1]; b2 = bp[2]; b3 = bp[3];
            }
#pragma unroll
            for (int ks = 0; ks < 4; ++ks) {
                double av0 = sA[(wr * 32 + ar_f) * 17 + ks * 4 + ak_f];
                double av1 = sA[(wr * 32 + 16 + ar_f) * 17 + ks * 4 + ak_f];
                double bv0 = sB[(ks * 4 + bk_f) * 68 + wc * 32 + bc_f];
                double bv1 = sB[(ks * 4 + bk_f) * 68 + wc * 32 + 16 + bc_f];
                acc[0][0] = __builtin_amdgcn_mfma_f64_16x16x4f64(av0, bv0, acc[0][0], 0, 0, 0);
                acc[0][1] = __builtin_amdgcn_mfma_f64_16x16x4f64(av0, bv1, acc[0][1], 0, 0, 0);
                acc[1][0] = __builtin_amdgcn_mfma_f64_16x16x4f64(av1, bv0, acc[1][0], 0, 0, 0);
                acc[1][1] = __builtin_amdgcn_mfma_f64_16x16x4f64(av1, bv1, acc[1][1], 0, 0, 0);
            }
        }
        __syncthreads();
        if (tid < 64) s2buf[tid] = 0.0;
        __syncthreads();
#pragma unroll
        for (int fi = 0; fi < 2; ++fi) {
#pragma unroll
            for (int d = 0; d < 4; ++d) {
                int localr = wr * 32 + fi * 16 + drr[d];
                int row = row0 + localr;
                int b = row / N_, nn = row - b * N_;
                double p = pol[row];
                double s2 = 0.0;
#pragma unroll
                for (int fj = 0; fj < 2; ++fj) {
                    int c = wc * 32 + fj * 16 + dcc[d];
                    double vv = acc[fi][fj][d] * p;
                    v32[(((size_t)(b * H_ + bx)) * N_ + nn) * HD_ + c] = (float)vv;
                    s2 += vv * vv;
                }
                atomicAdd(&s2buf[localr], s2);
            }
        }
        __syncthreads();
        if (tid < 64) atomicAdd(&vnorm2[row0 + tid], s2buf[tid]);
    } else {
        // ---------- VALU fallback ----------
        double (*As)[65] = (double (*)[65])sA;
        double (*Bs)[68] = (double (*)[68])sB;
        const int tx = tid & 15, ty = tid >> 4;
        const int arow = tid & 63, ak = (tid >> 6) * 4;
        const int brow = tid >> 4, bcol = (tid & 15) * 4;

        double acc[4][4];
#pragma unroll
        for (int i = 0; i < 4; ++i)
#pragma unroll
            for (int j = 0; j < 4; ++j) acc[i][j] = 0.0;

        const int gr = row0 + arow;
        for (int k0 = 0; k0 < C_; k0 += 16) {
            const double* ap = A + (size_t)gr * C_ + k0 + ak;
            double a0 = ap[0], a1 = ap[1], a2 = ap[2], a3 = ap[3];
            const double* bp = W + (size_t)(k0 + brow) * C3_ + 2 * C_ + col0 + bcol;
            double b0 = bp[0], b1 = bp[1], b2 = bp[2], b3 = bp[3];
            __syncthreads();
            As[ak + 0][arow] = a0; As[ak + 1][arow] = a1; As[ak + 2][arow] = a2; As[ak + 3][arow] = a3;
            Bs[brow][bcol + 0] = b0; Bs[brow][bcol + 1] = b1; Bs[brow][bcol + 2] = b2; Bs[brow][bcol + 3] = b3;
            __syncthreads();
#pragma unroll
            for (int kk = 0; kk < 16; ++kk) {
                double aa[4], bb[4];
#pragma unroll
                for (int i = 0; i < 4; ++i) aa[i] = As[kk][ty * 4 + i];
#pragma unroll
                for (int j = 0; j < 4; ++j) bb[j] = Bs[kk][tx + 16 * j];
#pragma unroll
                for (int i = 0; i < 4; ++i)
#pragma unroll
                    for (int j = 0; j < 4; ++j) acc[i][j] += aa[i] * bb[j];
            }
        }
#pragma unroll
        for (int i = 0; i < 4; ++i) {
            int row = row0 + ty * 4 + i;
            int b = row / N_, nn = row - b * N_;
            double p = pol[row];
            double s2 = 0.0;
#pragma unroll
            for (int j = 0; j < 4; ++j) {
                double vv = acc[i][j] * p;
                v32[(((size_t)(b * H_ + bx)) * N_ + nn) * HD_ + tx + 16 * j] = (float)vv;
                s2 += vv * vv;
            }
            s2 += __shfl_xor(s2, 1, 64);
            s2 += __shfl_xor(s2, 2, 64);
            s2 += __shfl_xor(s2, 4, 64);
            s2 += __shfl_xor(s2, 8, 64);
            if (tx == 0) atomicAdd(&vnorm2[row], s2);
        }
    }
}

// ---------------- MFMA split-bf16 GEMM: 128x128 tile, K-step 32 ----------------
struct Epi {
    const float* bias;
    const int* srctok;
    const void* xin;
    float* x2out;
    bf16* act;
    const float* x2in;
    void* dout;
    const int* flagp;
    float* qq; float* kk;
    const double* pol;
};

// MODE: 0 = qk scatter, 1 = proj -> x2, 2 = fc1 gelu -> act bf16, 3 = fc2 -> out
template <int MODE, bool SPLITA>
__global__ __launch_bounds__(256) void mgemm(const ushort_t* __restrict__ Ah,
                                             const ushort_t* __restrict__ Al,
                                             const ushort_t* __restrict__ Bh,
                                             const ushort_t* __restrict__ Bl,
                                             int M, int K, int NBX, Epi ep) {
    __shared__ ushort_t As_h[4096];
    __shared__ ushort_t As_l[4096];
    __shared__ ushort_t Bs_h[4096];
    __shared__ ushort_t Bs_l[4096];
    const int tid = threadIdx.x;
    const int lane = tid & 63, w = tid >> 6;
    const int wr = w >> 1, wc = w & 1;
    const int quad = lane >> 4, mn = lane & 15;
    int bx, by;
    xcd_decode(blockIdx.x, NBX * 99, NBX, bx, by);
    const int row0 = by * 128, col0 = bx * 128;

    floatx4 acc[4][4];
#pragma unroll
    for (int i = 0; i < 4; ++i)
#pragma unroll
        for (int j = 0; j < 4; ++j) acc[i][j] = floatx4{0.f, 0.f, 0.f, 0.f};

    const int srow = tid >> 2, soct = tid & 3;       // s=0 chunk
    const int srow2 = (tid + 256) >> 2;              // s=1 chunk (oct same)
    const int dst1 = (((srow >> 4) * 4 + soct) * 16 + (srow & 15)) * 8;
    const int dst2 = (((srow2 >> 4) * 4 + soct) * 16 + (srow2 & 15)) * 8;

    for (int k0 = 0; k0 < K; k0 += 32) {
        uint4 ah1, ah2, al1, al2, bh1, bh2, bl1, bl2;
        const uint4 zz = make_uint4(0, 0, 0, 0);
        {
            int gr = row0 + srow;
            size_t go = (size_t)gr * K + k0 + soct * 8;
            if (gr < M) { ah1 = *(const uint4*)(Ah + go); al1 = SPLITA ? *(const uint4*)(Al + go) : zz; }
            else        { ah1 = zz; al1 = zz; }
            gr = row0 + srow2;
            go = (size_t)gr * K + k0 + soct * 8;
            if (gr < M) { ah2 = *(const uint4*)(Ah + go); al2 = SPLITA ? *(const uint4*)(Al + go) : zz; }
            else        { ah2 = zz; al2 = zz; }
            size_t bo = (size_t)(col0 + srow) * K + k0 + soct * 8;
            bh1 = *(const uint4*)(Bh + bo); bl1 = *(const uint4*)(Bl + bo);
            bo = (size_t)(col0 + srow2) * K + k0 + soct * 8;
            bh2 = *(const uint4*)(Bh + bo); bl2 = *(const uint4*)(Bl + bo);
        }
        __syncthreads();
        *(uint4*)(As_h + dst1) = ah1; *(uint4*)(As_h + dst2) = ah2;
        if (SPLITA) { *(uint4*)(As_l + dst1) = al1; *(uint4*)(As_l + dst2) = al2; }
        *(uint4*)(Bs_h + dst1) = bh1; *(uint4*)(Bs_h + dst2) = bh2;
        *(uint4*)(Bs_l + dst1) = bl1; *(uint4*)(Bs_l + dst2) = bl2;
        __syncthreads();

        short8 afh[4], afl[4], bfh[4], bfl[4];
#pragma unroll
        for (int i = 0; i < 4; ++i) {
            int off = ((wr * 4 + i) * 64 + lane) * 8;
            afh[i] = *(const short8*)(As_h + off);
            if (SPLITA) afl[i] = *(const short8*)(As_l + off);
        }
#pragma unroll
        for (int j = 0; j < 4; ++j) {
            int off = ((wc * 4 + j) * 64 + lane) * 8;
            bfh[j] = *(const short8*)(Bs_h + off);
            bfl[j] = *(const short8*)(Bs_l + off);
        }
#pragma unroll
        for (int i = 0; i < 4; ++i)
#pragma unroll
            for (int j = 0; j < 4; ++j) {
                acc[i][j] = __builtin_amdgcn_mfma_f32_16x16x32_bf16(afh[i], bfh[j], acc[i][j], 0, 0, 0);
                acc[i][j] = __builtin_amdgcn_mfma_f32_16x16x32_bf16(afh[i], bfl[j], acc[i][j], 0, 0, 0);
                if (SPLITA)
                    acc[i][j] = __builtin_amdgcn_mfma_f32_16x16x32_bf16(afl[i], bfh[j], acc[i][j], 0, 0, 0);
            }
    }

    // epilogue: element (i,j,r): row = row0+wr*64+i*16+quad*4+r, col = col0+wc*64+j*16+mn
    if constexpr (MODE == 0) {
#pragma unroll
        for (int j = 0; j < 4; ++j) {
            int col = col0 + wc * 64 + j * 16 + mn;
            int comp = (col >= C_) ? 1 : 0;
            int rem = col - comp * C_;
            int hh = rem >> 6, d0 = rem & 63;
            float* dstbase = comp ? ep.kk : ep.qq;
#pragma unroll
            for (int i = 0; i < 4; ++i) {
                int rbase = row0 + wr * 64 + i * 16 + quad * 4;
#pragma unroll
                for (int r = 0; r < 4; ++r) {
                    int row = rbase + r; if (row >= M) continue;
                    int b = row / N_, nn = row - b * N_;
                    float pv = (float)ep.pol[row];
                    dstbase[(((size_t)(b * H_ + hh)) * N_ + nn) * HD_ + d0] = acc[i][j][r] * pv;
                }
            }
        }
    } else if constexpr (MODE == 1) {
        const bool f32 = (*ep.flagp != 0);
#pragma unroll
        for (int i = 0; i < 4; ++i) {
            int rbase = row0 + wr * 64 + i * 16 + quad * 4;
#pragma unroll
            for (int r = 0; r < 4; ++r) {
                int row = rbase + r; if (row >= M) continue;
                int st = ep.srctok[row];
                float polv = (st >= 0) ? 1.f : 0.f;
                int b = row / N_;
                size_t xrow = ((size_t)(b * N_ + (st < 0 ? 0 : st))) * C_;
#pragma unroll
                for (int j = 0; j < 4; ++j) {
                    int col = col0 + wc * 64 + j * 16 + mn;
                    float selx = (st >= 0) ? load_in(ep.xin, xrow + col, f32) : 0.f;
                    ep.x2out[(size_t)row * C_ + col] = selx + (acc[i][j][r] + ep.bias[col]) * polv;
                }
            }
        }
    } else if constexpr (MODE == 2) {
#pragma unroll
        for (int i = 0; i < 4; ++i) {
            int rbase = row0 + wr * 64 + i * 16 + quad * 4;
#pragma unroll
            for (int r = 0; r < 4; ++r) {
                int row = rbase + r; if (row >= M) continue;
#pragma unroll
                for (int j = 0; j < 4; ++j) {
                    int col = col0 + wc * 64 + j * 16 + mn;
                    float z = acc[i][j][r] + ep.bias[col];
                    float gl = 0.5f * z * (1.0f + erff(z * 0.70710678118654752f));
                    ep.act[(size_t)row * C4_ + col] = f2bf(gl);
                }
            }
        }
    } else {
        const bool f32out = (*ep.flagp != 0);
#pragma unroll
        for (int i = 0; i < 4; ++i) {
            int rbase = row0 + wr * 64 + i * 16 + quad * 4;
#pragma unroll
            for (int r = 0; r < 4; ++r) {
                int row = rbase + r; if (row >= M) continue;
                int st = ep.srctok[row];
                float polv = (st >= 0) ? 1.f : 0.f;
#pragma unroll
                for (int j = 0; j < 4; ++j) {
                    int col = col0 + wc * 64 + j * 16 + mn;
                    float val = (ep.x2in[(size_t)row * C_ + col] + acc[i][j][r] + ep.bias[col]) * polv;
                    size_t o = (size_t)row * C_ + col;
                    if (f32out) ((float*)ep.dout)[o] = val;
                    else        ((bf16*)ep.dout)[o] = f2bf(val);
                }
            }
        }
    }
}

// ---------------- attention probs (row stride KP_, zero-padded tail) ----------------
__global__ __launch_bounds__(256) void attn_kernel(const float* __restrict__ q,
                                                   const float* __restrict__ k,
                                                   const double* __restrict__ policy,
                                                   bf16* __restrict__ attn) {
    __shared__ float Ks[197 * 69];
    __shared__ float ps[256];
    const int bh = blockIdx.x, b = bh / H_;
    const int tid = threadIdx.x;
    const float* kbase = k + (size_t)bh * N_ * HD_;
    for (int idx = tid; idx < N_ * HD_; idx += 256) Ks[(idx >> 6) * 69 + (idx & 63)] = kbase[idx];
    for (int j = tid; j < 256; j += 256) ps[j] = (j < N_) ? (float)policy[b * N_ + j] : 0.f;
    __syncthreads();
    const int w = tid >> 6, lane = tid & 63;
    const int j0 = lane, j1 = lane + 64, j2 = lane + 128, j3 = lane + 192;
    const bool h3 = (lane < 5);
    const float* k0p = &Ks[j0 * 69];
    const float* k1p = &Ks[j1 * 69];
    const float* k2p = &Ks[j2 * 69];
    const float* k3p = h3 ? &Ks[j3 * 69] : &Ks[j0 * 69];
    const float p0 = ps[j0], p1 = ps[j1], p2 = ps[j2], p3 = h3 ? ps[j3] : 0.f;
    const float* qbase = q + (size_t)bh * N_ * HD_;
    for (int i = w; i < N_; i += 4) {
        const float* qr = qbase + i * HD_;
        float a0 = 0.f, a1 = 0.f, a2 = 0.f, a3 = 0.f;
#pragma unroll 8
        for (int d = 0; d < 64; ++d) {
            float qd = qr[d];
            a0 += qd * k0p[d]; a1 += qd * k1p[d]; a2 += qd * k2p[d]; a3 += qd * k3p[d];
        }
        float s0 = a0 * 0.125f, s1 = a1 * 0.125f, s2 = a2 * 0.125f;
        float s3 = h3 ? a3 * 0.125f : -INFINITY;
        float m = fmaxf(fmaxf(s0, s2), fmaxf(s1, s3));
        for (int off = 32; off > 0; off >>= 1) m = fmaxf(m, __shfl_down(m, off, 64));
        float mx = __shfl(m, 0, 64);
        float e0 = expf(s0 - mx) * (p0 + (1.f - p0) * ((j0 == i) ? 1.f : 0.f));
        float e1 = expf(s1 - mx) * (p1 + (1.f - p1) * ((j1 == i) ? 1.f : 0.f));
        float e2 = expf(s2 - mx) * (p2 + (1.f - p2) * ((j2 == i) ? 1.f : 0.f));
        float e3 = h3 ? expf(s3 - mx) * (p3 + (1.f - p3) * ((j3 == i) ? 1.f : 0.f)) : 0.f;
        float su = (e0 + e2) + (e1 + e3);
        for (int off = 32; off > 0; off >>= 1) su += __shfl_down(su, off, 64);
        float ssum = __shfl(su, 0, 64);
        bf16* orow = attn + ((size_t)bh * N_ + i) * KP_;
        orow[j0] = f2bf((e0 + 5.0761421319796954e-9f) / (ssum + 1e-6f));
        orow[j1] = f2bf((e1 + 5.0761421319796954e-9f) / (ssum + 1e-6f));
        orow[j2] = f2bf((e2 + 5.0761421319796954e-9f) / (ssum + 1e-6f));
        if (h3)               orow[j3] = f2bf((e3 + 5.0761421319796954e-9f) / (ssum + 1e-6f));
        else if (j3 < KP_)    orow[j3] = f2bf(0.f);   // zero pad cols 197..223
    }
}

// ---------------- fused score + sampling (decision path; score arithmetic verbatim) ----------------
DEV void bitonic_fi64(double* key, int* idx) {
    const int tid = threadIdx.x;
    for (int ksz = 2; ksz <= 256; ksz <<= 1)
        for (int jj = ksz >> 1; jj > 0; jj >>= 1) {
            __syncthreads();
            int ixj = tid ^ jj;
            if (ixj > tid) {
                double ka = key[tid], kb = key[ixj];
                int ia = idx[tid], ib = idx[ixj];
                bool up = (tid & ksz) == 0;
                bool agtb = (ka > kb) || (ka == kb && ia > ib);
                if (agtb == up) { key[tid] = kb; key[ixj] = ka; idx[tid] = ib; idx[ixj] = ia; }
            }
        }
    __syncthreads();
}
DEV void bitonic_int(int* a) {
    const int tid = threadIdx.x;
    for (int ksz = 2; ksz <= 256; ksz <<= 1)
        for (int jj = ksz >> 1; jj > 0; jj >>= 1) {
            __syncthreads();
            int ixj = tid ^ jj;
            if (ixj > tid) {
                int va = a[tid], vb = a[ixj];
                bool up = (tid & ksz) == 0;
                if ((va > vb) == up) { a[tid] = vb; a[ixj] = va; }
            }
        }
    __syncthreads();
}

__global__ __launch_bounds__(256) void sample_kernel(const double* __restrict__ cls,
                                                     const double* __restrict__ vnorm2,
                                                     int* __restrict__ srctok) {
    __shared__ double key[256];
    __shared__ int   idx[256];
    __shared__ double ncdf[196];
    __shared__ double red[256];
    __shared__ double sraw[256];
    __shared__ int   s1[256];
    __shared__ int   s2[256];
    __shared__ double cmm[2];
    const int b = blockIdx.x, tid = threadIdx.x;

    // --- score phase (identical arithmetic to old score_kernel) ---
    {
        const int t = tid;
        double raw = 0.0;
        if (t < N_) {
            double cs = 0.0;
            for (int h = 0; h < H_; ++h) cs += cls[(size_t)(b * H_ + h) * N_ + t];
            raw = cs * sqrt(vnorm2[b * N_ + t]);
        }
        double contrib = (t >= 1 && t < N_) ? raw : 0.0;
        double tot = bred_sum64(contrib, red);
        sraw[t] = raw;
        __syncthreads();
        key[tid] = (tid < NM1) ? (sraw[tid + 1] / tot) : INFINITY;
    }
    idx[tid] = tid;
    __syncthreads();
    bitonic_fi64(key, idx);

    if (tid == 0) {
        double c = 0.0, mn = INFINITY, mx = -INFINITY;
        for (int j = 0; j < NM1; ++j) {
            c += key[j]; ncdf[j] = c;
            mn = fmin(mn, c); mx = fmax(mx, c);
        }
        cmm[0] = mn; cmm[1] = mx;
    }
    __syncthreads();
    double cmin = cmm[0], cmax = cmm[1];
    if (tid < NM1) ncdf[tid] = (ncdf[tid] - cmin) / (cmax - cmin);
    __syncthreads();

    double vsm = (tid < NM1) ? (ncdf[tid] + ((ncdf[tid] == 0.0) ? 1e8 : 0.0)) : INFINITY;
    double ys_start = bred_min64(vsm, red);

    int tp = 0x7fffffff;
    if (tid < NM1) {
        double yj = (tid == 195) ? 1.0 : (double)tid * (1.0 / 195.0);
        double ys = ys_start + (yj * 195.0 - ys_start * (double)tid) / 195.0;
        double best = fabs(ys - ncdf[0]); int bj = 0;
        for (int j = 1; j < NM1; ++j) {
            double d = fabs(ys - ncdf[j]);
            if (d < best) { best = d; bj = j; }
        }
        tp = bj;
    }
    s1[tid] = tp; __syncthreads();
    bitonic_int(s1);

    int u = 0x7fffffff;
    if (tid < NM1) {
        int sv = s1[tid];
        int nxt = (tid < NM1 - 1) ? s1[tid + 1] : 1;
        u = (nxt == sv) ? NM1 : sv;
    }
    __syncthreads();
    s2[tid] = u; __syncthreads();
    bitonic_int(s2);

    if (tid < N_) {
        int st;
        if (tid == 0) st = 0;
        else {
            int uu = s2[tid - 1];
            st = (uu == NM1) ? -1 : (1 + idx[uu]);
        }
        srctok[(size_t)b * N_ + tid] = st;
    }
}

// ---------------- xo = gathered_attn @ v via bf16 MFMA, split output ----------------
__global__ __launch_bounds__(256) void av_mfma(const bf16* __restrict__ attn,
                                               const float* __restrict__ v,
                                               const int* __restrict__ srctok,
                                               ushort_t* __restrict__ xoh,
                                               ushort_t* __restrict__ xol) {
    __shared__ ushort_t Bsh[4 * 7 * 4 * 16 * 8];   // 14336
    __shared__ ushort_t Bsl[4 * 7 * 4 * 16 * 8];
    const int bh = blockIdx.x, b = bh / H_, hd = bh - b * H_;
    const int tid = threadIdx.x, lane = tid & 63, w = tid >> 6;
    const int mn = lane & 15, oct = lane >> 4;

#pragma unroll
    for (int cf = 0; cf < 4; ++cf) {
        int base = (cf * 7 + 6) * 512;
        for (int o = tid; o < 512; o += 256) { Bsh[base + o] = 0; Bsl[base + o] = 0; }
    }
    __syncthreads();
    const float* vb = v + (size_t)bh * (N_ * HD_);
    for (int idx = tid; idx < N_ * HD_; idx += 256) {
        int m = idx >> 6, d = idx & 63;
        ushort_t h, l; split_bf(vb[idx], h, l);
        int o = ((((d >> 4) * 7 + (m >> 5)) * 4 + ((m >> 3) & 3)) * 16 + (d & 15)) * 8 + (m & 7);
        Bsh[o] = h; Bsl[o] = l;
    }
    __syncthreads();

    const int nf = (w == 0) ? 4 : 3;
    const int frg[4] = { w, w + 4, w + 8, 12 };

    floatx4 acc[4][4];
#pragma unroll
    for (int f = 0; f < 4; ++f)
#pragma unroll
        for (int cf = 0; cf < 4; ++cf) acc[f][cf] = floatx4{0.f, 0.f, 0.f, 0.f};

    size_t abase[4]; bool aval[4];
#pragma unroll
    for (int f = 0; f < 4; ++f) {
        int row = frg[f] * 16 + mn;
        int st = (f < nf && row < N_) ? srctok[b * N_ + row] : -1;
        aval[f] = (st >= 0);
        abase[f] = ((size_t)bh * N_ + (st < 0 ? 0 : st)) * KP_ + oct * 8;
    }

    const short8 z8 = short8{0, 0, 0, 0, 0, 0, 0, 0};
    const ushort_t* ap = (const ushort_t*)attn;
    for (int ks = 0; ks < 7; ++ks) {
        const int k0 = ks * 32;
        short8 af[4];
#pragma unroll
        for (int f = 0; f < 4; ++f)
            af[f] = aval[f] ? *(const short8*)(ap + abase[f] + k0) : z8;
#pragma unroll
        for (int cf = 0; cf < 4; ++cf) {
            int bo = (((cf * 7 + ks) * 4 + oct) * 16 + mn) * 8;
            short8 bh8 = *(const short8*)(Bsh + bo);
            short8 bl8 = *(const short8*)(Bsl + bo);
#pragma unroll
            for (int f = 0; f < 4; ++f) {
                if (f < nf) {
                    acc[f][cf] = __builtin_amdgcn_mfma_f32_16x16x32_bf16(af[f], bh8, acc[f][cf], 0, 0, 0);
                    acc[f][cf] = __builtin_amdgcn_mfma_f32_16x16x32_bf16(af[f], bl8, acc[f][cf], 0, 0, 0);
                }
            }
        }
    }

    const int quad = lane >> 4;
#pragma unroll
    for (int f = 0; f < 4; ++f) {
        if (f >= nf) continue;
#pragma unroll
        for (int r = 0; r < 4; ++r) {
            int row = frg[f] * 16 + quad * 4 + r;
            if (row >= N_) continue;
            size_t ob = ((size_t)(b * N_) + row) * C_ + hd * 64;
#pragma unroll
            for (int cf = 0; cf < 4; ++cf) {
                ushort_t h, l; split_bf(acc[f][cf][r], h, l);
                xoh[ob + cf * 16 + mn] = h;
                xol[ob + cf * 16 + mn] = l;
            }
        }
    }
}

// ---------------- launch ----------------
extern "C" void kernel_launch(void* const* d_in, const int* in_sizes, int n_in,
                              void* d_out, int out_size, void* d_ws, size_t ws_size,
                              hipStream_t stream) {
    char* ws = (char*)d_ws;
    int*      flag     = (int*)     (ws + 0);
    int*      mfmamode = (int*)     (ws + 64);
    double*   w64      = (double*)  (ws + 256);          // 14,155,776
    ushort_t* wqkvT_h  = (ushort_t*)(ws + 14156032);     //  2,359,296
    ushort_t* wqkvT_l  = (ushort_t*)(ws + 16515328);     //  2,359,296
    ushort_t* wprojT_h = (ushort_t*)(ws + 18874624);     //  1,179,648
    ushort_t* wprojT_l = (ushort_t*)(ws + 20054272);     //  1,179,648
    ushort_t* wfc1T_h  = (ushort_t*)(ws + 21233920);     //  4,718,592
    ushort_t* wfc1T_l  = (ushort_t*)(ws + 25952512);     //  4,718,592
    ushort_t* wfc2T_h  = (ushort_t*)(ws + 30671104);     //  4,718,592
    ushort_t* wfc2T_l  = (ushort_t*)(ws + 35389696);     //  4,718,592
    double*   pol64    = (double*)  (ws + 40108288);     //    100,864
    double*   g1_64    = (double*)  (ws + 40209152);     //      6,144
    double*   b1_64    = (double*)  (ws + 40215296);     //      6,144
    float*    g2_32    = (float*)   (ws + 40221440);     //      3,072
    float*    b2_32    = (float*)   (ws + 40224512);     //      3,072
    float*    bproj32  = (float*)   (ws + 40227584);     //      3,072
    float*    bfc1_32  = (float*)   (ws + 40230656);     //     12,288
    float*    bfc2_32  = (float*)   (ws + 40242944);     //      3,072
    double*   q0_64    = (double*)  (ws + 40246016);     //    393,216
    double*   wq0_64   = (double*)  (ws + 40639232);     //  4,718,592
    double*   vnorm2   = (double*)  (ws + 45357824);     //    100,864
    double*   cls64    = (double*)  (ws + 45458688);     //  1,210,368
    double*   score64  = (double*)  (ws + 46669056);     //    100,352 (unused, kept for layout)
    int*      srctok   = (int*)     (ws + 46769408);     //     50,432
    // big slots (lifetime-sequenced):
    double*   xn64     = (double*)  (ws + 48000000);     // 77,463,552
    bf16*     attn     = (bf16*)    (ws + 48000000);     // 67,768,320
    bf16*     act      = (bf16*)    (ws + 48000000);     // 77,463,552
    ushort_t* xn_h     = (ushort_t*)(ws + 125463552);    // 19,365,888
    ushort_t* xn_l     = (ushort_t*)(ws + 144829440);    // 19,365,888
    float*    v32      = (float*)   (ws + 125463552);    // 38,731,776
    float*    q32      = (float*)   (ws + 164195328);    // 38,731,776
    ushort_t* xo_h     = (ushort_t*)(ws + 164195328);    // 19,365,888
    ushort_t* xo_l     = (ushort_t*)(ws + 183561216);    // 19,365,888
    ushort_t* h1_h     = (ushort_t*)(ws + 164195328);    // 19,365,888
    ushort_t* h1_l     = (ushort_t*)(ws + 183561216);    // 19,365,888
    float*    k32      = (float*)   (ws + 202927104);    // 38,731,776
    float*    x2_32    = (float*)   (ws + 202927104);    // 38,731,776
    (void)score64;

    const dim3 blk(256);

    // 0) dtype detect + fused conversions/probe + weight transposes
    detect_kernel<<<1, blk, 0, stream>>>((const ushort_t*)d_in[2], flag);
    { PrepArgs a;
      a.bproj_s = d_in[4]; a.g1_s = d_in[5]; a.b1_s = d_in[6]; a.g2_s = d_in[7];
      a.b2_s = d_in[8]; a.bfc1_s = d_in[10]; a.bfc2_s = d_in[12]; a.pol_s = d_in[1];
      a.bproj_d = bproj32; a.g2_d = g2_32; a.b2_d = b2_32; a.bfc1_d = bfc1_32; a.bfc2_d = bfc2_32;
      a.g1_d = g1_64; a.b1_d = b1_64; a.pol_d = pol64; a.vn_d = vnorm2;
      a.mode = mfmamode; a.flag = flag;
      prep_small<<<131, blk, 0, stream>>>(a); }
    cvt64_kernel<<<1024, blk, 0, stream>>>(d_in[2], w64, C_ * C3_, flag);
    { TSArgs a;
      a.w0 = d_in[2];  a.h0 = wqkvT_h;  a.l0 = wqkvT_l;
      a.w1 = d_in[3];  a.h1 = wprojT_h; a.l1 = wprojT_l;
      a.w2 = d_in[9];  a.h2 = wfc1T_h;  a.l2 = wfc1T_l;
      a.w3 = d_in[11]; a.h3 = wfc2T_h;  a.l3 = wfc2T_l;
      a.flag = flag;
      tsplit_all<<<6336, blk, 0, stream>>>(a); }

    // 1) LN1 fp64 (+ split copy)
    ln64_kernel<<<M_, blk, 0, stream>>>(d_in[0], g1_64, b1_64, xn64, xn_h, xn_l, flag);

    // 2) fp64 score-path precursors (parallelized grids)
    q0_kernel<<<dim3(B_, 3), blk, 0, stream>>>(xn64, w64, pol64, q0_64);
    wq0_kernel<<<dim3(B_, 3), blk, 0, stream>>>(w64, q0_64, wq0_64);

    // 3) q,k via bf16 MFMA GEMM (A = xn hi-only; q/k are off the decision path —
    //    srctok derives solely from fp64 q0/wq0/cls + vnorm2)
    { Epi e = {}; e.qq = q32; e.kk = k32; e.pol = pol64;
      mgemm<0, false><<<12 * 99, blk, 0, stream>>>(xn_h, xn_l, wqkvT_h, wqkvT_l, M_, C_, 12, e); }

    // 4) v fp64 GEMM v2 (decision path, 64x64 tile, XCD-swizzled) -> v32 + vnorm2
    gemm64v2<<<12 * 197, blk, 0, stream>>>(xn64, w64, pol64, v32, vnorm2, mfmamode);

    // 5) cls rows fp64 (ph split across blockIdx.y; last use of xn64)
    cls_kernel<<<dim3(B_, 2), blk, 0, stream>>>(xn64, wq0_64, pol64, cls64);

    // 6) attention probs (writes SL1 over dead xn64, stride KP_)
    attn_kernel<<<BH_, blk, 0, stream>>>(q32, k32, pol64, attn);

    // 7) fused score + sampling
    sample_kernel<<<B_, blk, 0, stream>>>(cls64, vnorm2, srctok);

    // 8) xo = gathered attn @ v via MFMA -> split (SL3 over dead q32)
    av_mfma<<<BH_, blk, 0, stream>>>(attn, v32, srctok, xo_h, xo_l);

    // 9) proj MFMA -> x2 (A = xo hi-only)
    { Epi e = {}; e.bias = bproj32; e.srctok = srctok; e.xin = d_in[0]; e.x2out = x2_32; e.flagp = flag;
      mgemm<1, false><<<6 * 99, blk, 0, stream>>>(xo_h, xo_l, wprojT_h, wprojT_l, M_, C_, 6, e); }

    // 10) LN2 fp32 -> h1 split (SL3 over dead xo)
    ln32_kernel<<<M_, blk, 0, stream>>>(x2_32, g2_32, b2_32, h1_h, h1_l);

    // 11) fc1 MFMA + GELU -> act bf16 (A = h1 hi-only)
    { Epi e = {}; e.bias = bfc1_32; e.act = act;
      mgemm<2, false><<<24 * 99, blk, 0, stream>>>(h1_h, h1_l, wfc1T_h, wfc1T_l, M_, C_, 24, e); }

    // 12) fc2 MFMA (bf16 act as A-hi) + residual + pol -> out
    { Epi e = {}; e.bias = bfc2_32; e.srctok = srctok; e.x2in = x2_32; e.dout = d_out; e.flagp = flag;
      mgemm<3, false><<<6 * 99, blk, 0, stream>>>((const ushort_t*)act, nullptr, wfc2T_h, wfc2T_l, M_, C4_, 6, e); }
}

// Round 15
// 1575.900 us; speedup vs baseline: 1.0135x; 1.0135x over previous
//
#include <hip/hip_runtime.h>
#include <hip/hip_bf16.h>
#include <cmath>

typedef __hip_bfloat16 bf16;
typedef unsigned short ushort_t;
typedef __attribute__((ext_vector_type(8))) short short8;
typedef __attribute__((ext_vector_type(4))) float floatx4;
typedef __attribute__((ext_vector_type(4))) double f64x4;
#define DEV static __device__ __forceinline__

DEV float bf2f(bf16 x) { return __bfloat162float(x); }
DEV bf16  f2bf(float x) { return __float2bfloat16(x); }

constexpr int B_  = 64, N_ = 197, C_ = 768, H_ = 12, HD_ = 64;
constexpr int C3_ = 3 * C_;      // 2304
constexpr int C4_ = 4 * C_;      // 3072
constexpr int M_  = B_ * N_;     // 12608
constexpr int BH_ = B_ * H_;     // 768
constexpr int NM1 = N_ - 1;      // 196
constexpr int KP_ = 224;         // padded attn row stride (7 x 32)

DEV ushort_t bfbits(bf16 b) { union { bf16 b; ushort_t u; } cv; cv.b = b; return cv.u; }
DEV void split_bf(float x, ushort_t& h, ushort_t& l) {
    bf16 bh = f2bf(x);
    float fh = bf2f(bh);
    bf16 bl = f2bf(x - fh);
    h = bfbits(bh); l = bfbits(bl);
}

// XCD-chunked bijective swizzle (m204)
DEV void xcd_decode(int g, int total, int nbx, int& bx, int& by) {
    const int q = total >> 3, r = total & 7;
    const int k = g & 7, s = g >> 3;
    const int w = (k < r) ? k * (q + 1) + s : r * (q + 1) + (k - r) * q + s;
    by = w / nbx; bx = w - by * nbx;
}

// wave-level f64/f32 butterfly sums (all lanes end with total)
DEV double wred64(double v) {
#pragma unroll
    for (int off = 32; off > 0; off >>= 1) v += __shfl_xor(v, off, 64);
    return v;
}
DEV float wred32(float v) {
#pragma unroll
    for (int off = 32; off > 0; off >>= 1) v += __shfl_xor(v, off, 64);
    return v;
}

// ================= f64 MFMA layout machinery =================
DEV void lay_a(int ia, int l, int& r, int& k) {
    if (ia == 0) { r = l & 15; k = l >> 4; }
    else         { r = l >> 2; k = l & 3;  }
}
DEV void lay_b(int ib, int l, int& k, int& c) {
    if (ib == 0) { k = l >> 4; c = l & 15; }
    else         { k = l & 3;  c = l >> 2; }
}
DEV void lay_d(int id, int l, int d, int& r, int& c) {
    int g = l >> 4, m = l & 15;
    switch (id) {
        case 0:  r = g * 4 + d; c = m; break;
        case 1:  r = g + 4 * d; c = m; break;
        case 2:  r = m; c = g * 4 + d; break;
        default: r = m; c = g + 4 * d; break;
    }
}
DEV int at_val(int i, int k) { return 1 + ((5 * i + 13 * k + 7 * i * k) % 29); }
DEV int bt_val(int k, int j) { return 1 + ((7 * j + 11 * k + 3 * j * k) % 23); }

// hardware-verified-at-runtime f64 MFMA layout probe (exact integer check)
DEV void probe_body(int l, int* mode) {
    int best = -1, nbest = 0;
    for (int ia = 0; ia < 2; ++ia) {
        for (int ib = 0; ib < 2; ++ib) {
            int ar, ak, bk, bc;
            lay_a(ia, l, ar, ak);
            lay_b(ib, l, bk, bc);
            double av = (double)at_val(ar, ak);
            double bv = (double)bt_val(bk, bc);
            f64x4 dd = {0.0, 0.0, 0.0, 0.0};
            dd = __builtin_amdgcn_mfma_f64_16x16x4f64(av, bv, dd, 0, 0, 0);
            for (int id = 0; id < 4; ++id) {
                int ok = 1;
                for (int d = 0; d < 4; ++d) {
                    int rr, cc; lay_d(id, l, d, rr, cc);
                    double ref = 0.0;
                    for (int k = 0; k < 4; ++k)
                        ref += (double)(at_val(rr, k) * bt_val(k, cc));
                    if (dd[d] != ref) ok = 0;
                }
                if (__all(ok)) { best = ia * 8 + ib * 4 + id; ++nbest; }
            }
        }
    }
    if (l == 0) *mode = (nbest == 1) ? (16 + best) : 0;
}

// ---------------- dtype detection ----------------
__global__ __launch_bounds__(256) void detect_kernel(const ushort_t* __restrict__ w,
                                                     int* __restrict__ flag) {
    __shared__ int cnt;
    if (threadIdx.x == 0) cnt = 0;
    __syncthreads();
    int c = 0;
#pragma unroll
    for (int k = 0; k < 8; ++k) {
        ushort_t u = w[threadIdx.x * 8 + k];
        int e = (u >> 7) & 0xFF;
        if (e >= 143) ++c;
    }
    atomicAdd(&cnt, c);
    __syncthreads();
    if (threadIdx.x == 0) *flag = (cnt >= 8) ? 1 : 0;   // 1 = fp32 inputs
}

DEV float load_in(const void* p, size_t i, bool f32) {
    return f32 ? ((const float*)p)[i] : bf2f(((const bf16*)p)[i]);
}

// ---------------- converters ----------------
__global__ __launch_bounds__(256) void cvt64_kernel(const void* __restrict__ s, double* __restrict__ d,
                                                    int n, const int* __restrict__ flag) {
    const bool f32 = (*flag != 0);
    int i = blockIdx.x * 256 + threadIdx.x, st = gridDim.x * 256;
    for (; i < n; i += st) d[i] = (double)load_in(s, i, f32);
}

// fused small conversions + vnorm2 zero + f64-MFMA probe (bid 130)
struct PrepArgs {
    const void *bproj_s, *g1_s, *b1_s, *g2_s, *b2_s, *bfc1_s, *bfc2_s, *pol_s;
    float *bproj_d, *g2_d, *b2_d, *bfc1_d, *bfc2_d;
    double *g1_d, *b1_d, *pol_d, *vn_d;
    int* mode;
    const int* flag;
};
__global__ __launch_bounds__(256) void prep_small(PrepArgs a) {
    const bool f32 = (*a.flag != 0);
    const int bid = blockIdx.x, tid = threadIdx.x;
    if (bid < 3)       { int i = bid * 256 + tid;        a.bproj_d[i] = load_in(a.bproj_s, i, f32); }
    else if (bid < 6)  { int i = (bid - 3) * 256 + tid;  a.g1_d[i] = (double)load_in(a.g1_s, i, f32); }
    else if (bid < 9)  { int i = (bid - 6) * 256 + tid;  a.b1_d[i] = (double)load_in(a.b1_s, i, f32); }
    else if (bid < 12) { int i = (bid - 9) * 256 + tid;  a.g2_d[i] = load_in(a.g2_s, i, f32); }
    else if (bid < 15) { int i = (bid - 12) * 256 + tid; a.b2_d[i] = load_in(a.b2_s, i, f32); }
    else if (bid < 18) { int i = (bid - 15) * 256 + tid; a.bfc2_d[i] = load_in(a.bfc2_s, i, f32); }
    else if (bid < 30) { int i = (bid - 18) * 256 + tid; a.bfc1_d[i] = load_in(a.bfc1_s, i, f32); }
    else if (bid < 80) { int i = (bid - 30) * 256 + tid; if (i < M_) a.pol_d[i] = (double)load_in(a.pol_s, i, f32); }
    else if (bid < 130){ int i = (bid - 80) * 256 + tid; if (i < M_) a.vn_d[i] = 0.0; }
    else               { if (tid < 64) probe_body(tid, a.mode); }
}

// ---------------- merged weight transpose + split (4 segments, 1 launch) ----------------
struct TSArgs {
    const void *w0, *w1, *w2, *w3;
    ushort_t *h0, *l0, *h1, *l1, *h2, *l2, *h3, *l3;
    const int* flag;
};
__global__ __launch_bounds__(256) void tsplit_all(TSArgs a) {
    __shared__ float t[32][33];
    const bool f32 = (*a.flag != 0);
    const int tid = threadIdx.x;
    int bid = blockIdx.x;
    const void* W; ushort_t *hi; ushort_t *lo; int K, Nstride, nbx;
    if (bid < 1152)      {              W = a.w0; hi = a.h0; lo = a.l0; K = C_;  Nstride = C3_; nbx = 48; }
    else if (bid < 1728) { bid -= 1152; W = a.w1; hi = a.h1; lo = a.l1; K = C_;  Nstride = C_;  nbx = 24; }
    else if (bid < 4032) { bid -= 1728; W = a.w2; hi = a.h2; lo = a.l2; K = C_;  Nstride = C4_; nbx = 96; }
    else                 { bid -= 4032; W = a.w3; hi = a.h3; lo = a.l3; K = C4_; Nstride = C_;  nbx = 24; }
    const int n0 = (bid % nbx) * 32, k0 = (bid / nbx) * 32;
    for (int idx = tid; idx < 1024; idx += 256) {
        int kk = idx >> 5, nn = idx & 31;
        t[kk][nn] = load_in(W, (size_t)(k0 + kk) * Nstride + n0 + nn, f32);
    }
    __syncthreads();
    for (int idx = tid; idx < 1024; idx += 256) {
        int nn = idx >> 5, kk = idx & 31;
        ushort_t h, l; split_bf(t[kk][nn], h, l);
        size_t o = (size_t)(n0 + nn) * K + k0 + kk;
        hi[o] = h; lo[o] = l;
    }
}

// ---------------- block reductions (kept for sample) ----------------
DEV double bred_sum64(double v, double* red) {
    int t = threadIdx.x; red[t] = v; __syncthreads();
    for (int s = 128; s > 0; s >>= 1) { if (t < s) red[t] += red[t + s]; __syncthreads(); }
    double r = red[0]; __syncthreads(); return r;
}
DEV double bred_min64(double v, double* red) {
    int t = threadIdx.x; red[t] = v; __syncthreads();
    for (int s = 128; s > 0; s >>= 1) { if (t < s) red[t] = fmin(red[t], red[t + s]); __syncthreads(); }
    double r = red[0]; __syncthreads(); return r;
}

// ---------------- LN1 fp64 (wave-shfl reduction): raw x -> xn64 + xn hi/lo ----------------
__global__ __launch_bounds__(256) void ln64_kernel(const void* __restrict__ in,
                                                   const double* __restrict__ g,
                                                   const double* __restrict__ bb,
                                                   double* __restrict__ out,
                                                   ushort_t* __restrict__ oh,
                                                   ushort_t* __restrict__ ol,
                                                   const int* __restrict__ flag) {
    __shared__ double part[4];
    __shared__ double part2[4];
    const bool f32 = (*flag != 0);
    const int tid = threadIdx.x, lane = tid & 63, w = tid >> 6;
    const size_t row = blockIdx.x;
    double x0 = (double)load_in(in, row * C_ + tid, f32);
    double x1 = (double)load_in(in, row * C_ + tid + 256, f32);
    double x2 = (double)load_in(in, row * C_ + tid + 512, f32);
    double s = wred64(x0 + x1 + x2);
    if (lane == 0) part[w] = s;
    __syncthreads();
    double m = (part[0] + part[1] + part[2] + part[3]) / 768.0;
    double d0 = x0 - m, d1 = x1 - m, d2 = x2 - m;
    double vv = wred64(d0 * d0 + d1 * d1 + d2 * d2);
    if (lane == 0) part2[w] = vv;
    __syncthreads();
    double var = (part2[0] + part2[1] + part2[2] + part2[3]) / 768.0;
    double istd = 1.0 / sqrt(var + 1e-5);
    double* op = out + row * C_;
    double v0 = (d0 * istd) * g[tid]     + bb[tid];
    double v1 = (d1 * istd) * g[tid+256] + bb[tid+256];
    double v2 = (d2 * istd) * g[tid+512] + bb[tid+512];
    op[tid] = v0; op[tid+256] = v1; op[tid+512] = v2;
    ushort_t h, l;
    split_bf((float)v0, h, l); oh[row*C_+tid]     = h; ol[row*C_+tid]     = l;
    split_bf((float)v1, h, l); oh[row*C_+tid+256] = h; ol[row*C_+tid+256] = l;
    split_bf((float)v2, h, l); oh[row*C_+tid+512] = h; ol[row*C_+tid+512] = l;
}

// ---------------- LN2 fp32 (wave-shfl reduction) -> h1 hi/lo ----------------
__global__ __launch_bounds__(256) void ln32_kernel(const float* __restrict__ in,
                                                   const float* __restrict__ g,
                                                   const float* __restrict__ bb,
                                                   ushort_t* __restrict__ oh,
                                                   ushort_t* __restrict__ ol) {
    __shared__ float part[4];
    __shared__ float part2[4];
    const int tid = threadIdx.x, lane = tid & 63, w = tid >> 6;
    const size_t row = blockIdx.x;
    const float* xp = in + row * C_;
    float x0 = xp[tid], x1 = xp[tid + 256], x2 = xp[tid + 512];
    float s = wred32(x0 + x1 + x2);
    if (lane == 0) part[w] = s;
    __syncthreads();
    float m = (part[0] + part[1] + part[2] + part[3]) * (1.0f / 768.0f);
    float d0 = x0 - m, d1 = x1 - m, d2 = x2 - m;
    float vv = wred32(d0 * d0 + d1 * d1 + d2 * d2);
    if (lane == 0) part2[w] = vv;
    __syncthreads();
    float var = (part2[0] + part2[1] + part2[2] + part2[3]) * (1.0f / 768.0f);
    float istd = 1.0f / sqrtf(var + 1e-5f);
    ushort_t h, l;
    split_bf(d0 * istd * g[tid]     + bb[tid],     h, l); oh[row*C_+tid]     = h; ol[row*C_+tid]     = l;
    split_bf(d1 * istd * g[tid+256] + bb[tid+256], h, l); oh[row*C_+tid+256] = h; ol[row*C_+tid+256] = l;
    split_bf(d2 * istd * g[tid+512] + bb[tid+512], h, l); oh[row*C_+tid+512] = h; ol[row*C_+tid+512] = l;
}

// ---------------- q0 / wq0 / cls (decision path; grid-reshaped, arithmetic identical) ----------------
__global__ __launch_bounds__(256) void q0_kernel(const double* __restrict__ xn64,
                                                 const double* __restrict__ w64,
                                                 const double* __restrict__ pol,
                                                 double* __restrict__ q0) {
    const int b = blockIdx.x;
    const int j = blockIdx.y * 256 + threadIdx.x;
    const double* xr = xn64 + (size_t)(b * N_) * C_;
    double p0 = pol[b * N_];
    double acc = 0.0;
    for (int c = 0; c < C_; ++c) acc += xr[c] * w64[(size_t)c * C3_ + j];
    q0[(size_t)b * C_ + j] = acc * p0;
}

__global__ __launch_bounds__(256) void wq0_kernel(const double* __restrict__ w64,
                                                  const double* __restrict__ q0,
                                                  double* __restrict__ wq0) {
    const int b = blockIdx.x, tid = threadIdx.x;
    const int base = blockIdx.y * 3072, lim = base + 3072;
    for (int idx = base + tid; idx < lim; idx += 256) {
        int h = idx / C_, c = idx - h * C_;
        const double* wr = w64 + (size_t)c * C3_ + C_ + h * HD_;
        const double* qr = q0 + (size_t)b * C_ + h * HD_;
        double acc = 0.0;
#pragma unroll 8
        for (int d = 0; d < HD_; ++d) acc += wr[d] * qr[d];
        wq0[((size_t)b * H_ + h) * C_ + c] = acc;
    }
}

__global__ __launch_bounds__(256) void cls_kernel(const double* __restrict__ xn64,
                                                  const double* __restrict__ wq0,
                                                  const double* __restrict__ pol,
                                                  double* __restrict__ cls) {
    __shared__ double wsh[6][768];
    __shared__ double sarr[6][200];
    const int b = blockIdx.x;
    const int ph = blockIdx.y;
    const int tid = threadIdx.x, w = tid >> 6, lane = tid & 63;
    for (int idx = tid; idx < 6 * 768; idx += 256) {
        int h = idx / 768, c = idx - h * 768;
        wsh[h][c] = wq0[((size_t)b * H_ + ph * 6 + h) * C_ + c];
    }
    __syncthreads();
    for (int t = w; t < N_; t += 4) {
        const double* xr = xn64 + (size_t)(b * N_ + t) * C_;
        double xreg[12];
#pragma unroll
        for (int ch = 0; ch < 12; ++ch) xreg[ch] = xr[ch * 64 + lane];
        double pm = pol[b * N_ + t] * 0.125;
        for (int h = 0; h < 6; ++h) {
            double acc = 0.0;
#pragma unroll
            for (int ch = 0; ch < 12; ++ch) acc += xreg[ch] * wsh[h][ch * 64 + lane];
            for (int off = 32; off > 0; off >>= 1) acc += __shfl_down(acc, off, 64);
            if (lane == 0) sarr[h][t] = acc * pm;
        }
    }
    __syncthreads();
    for (int hh = w; hh < 6; hh += 4) {
        const int j0 = lane, j1 = lane + 64, j2 = lane + 128, j3 = lane + 192;
        const bool h3 = (lane < 5);
        double s0 = sarr[hh][j0], s1 = sarr[hh][j1], s2 = sarr[hh][j2];
        double s3 = h3 ? sarr[hh][j3] : -INFINITY;
        double m = fmax(fmax(s0, s2), fmax(s1, s3));
        for (int off = 32; off > 0; off >>= 1) m = fmax(m, __shfl_down(m, off, 64));
        double mx = __shfl(m, 0, 64);
        double p0 = pol[b * N_ + j0], p1 = pol[b * N_ + j1], p2 = pol[b * N_ + j2];
        double e0 = exp(s0 - mx) * (p0 + (1.0 - p0));
        if (j0 != 0) e0 = exp(s0 - mx) * p0;
        double e1 = exp(s1 - mx) * p1;
        double e2 = exp(s2 - mx) * p2;
        double e3 = 0.0;
        if (h3) { double p3 = pol[b * N_ + j3]; e3 = exp(s3 - mx) * p3; }
        double su = (e0 + e2) + (e1 + e3);
        for (int off = 32; off > 0; off >>= 1) su += __shfl_down(su, off, 64);
        double ssum = __shfl(su, 0, 64);
        double* crow = cls + ((size_t)b * H_ + ph * 6 + hh) * N_;
        crow[j0] = (e0 + 1e-6 / 197.0) / (ssum + 1e-6);
        crow[j1] = (e1 + 1e-6 / 197.0) / (ssum + 1e-6);
        crow[j2] = (e2 + 1e-6 / 197.0) / (ssum + 1e-6);
        if (h3) crow[j3] = (e3 + 1e-6 / 197.0) / (ssum + 1e-6);
    }
}

// ---------------- V GEMM v2 (round-8 proven): 64x64 tile, dual path ----------------
__global__ __launch_bounds__(256) void gemm64v2(const double* __restrict__ A,
                                                const double* __restrict__ W,
                                                const double* __restrict__ pol,
                                                float* __restrict__ v32,
                                                double* __restrict__ vnorm2,
                                                const int* __restrict__ modep) {
    __shared__ double sA[64 * 17 + 8];   // MFMA: [row][17] ; VALU view: [16][65]
    __shared__ double sB[16 * 68];       // [k][68] both paths
    __shared__ double s2buf[64];
    const int mode = *modep;
    const int tid = threadIdx.x;
    int bx, by;
    xcd_decode(blockIdx.x, 12 * 197, 12, bx, by);
    const int row0 = by * 64, col0 = bx * 64;

    if (mode >= 16) {
        // ---------- f64 MFMA path (register-prefetched) ----------
        const int lane = tid & 63, w = tid >> 6;
        const int wr = w >> 1, wc = w & 1;
        const int cb = mode - 16, ia = cb >> 3, ib = (cb >> 2) & 1, idm = cb & 3;
        int ar_f, ak_f, bk_f, bc_f;
        lay_a(ia, lane, ar_f, ak_f);
        lay_b(ib, lane, bk_f, bc_f);
        int drr[4], dcc[4];
#pragma unroll
        for (int d = 0; d < 4; ++d) lay_d(idm, lane, d, drr[d], dcc[d]);

        f64x4 acc[2][2];
#pragma unroll
        for (int i = 0; i < 2; ++i)
#pragma unroll
            for (int j = 0; j < 2; ++j) acc[i][j] = f64x4{0.0, 0.0, 0.0, 0.0};

        const int arow = tid >> 2, akk = (tid & 3) * 4;
        const int bk2 = tid >> 4, bc2 = (tid & 15) * 4;
        const double* aptr = A + (size_t)(row0 + arow) * C_ + akk;
        const double* bptr = W + (size_t)bk2 * C3_ + 2 * C_ + col0 + bc2;

        double a0 = aptr[0], a1 = aptr[1], a2 = aptr[2], a3 = aptr[3];
        double b0 = bptr[0], b1 = bptr[1], b2 = bptr[2], b3 = bptr[3];

        for (int k0 = 0; k0 < C_; k0 += 16) {
            __syncthreads();
            sA[arow * 17 + akk + 0] = a0; sA[arow * 17 + akk + 1] = a1;
            sA[arow * 17 + akk + 2] = a2; sA[arow * 17 + akk + 3] = a3;
            sB[bk2 * 68 + bc2 + 0] = b0; sB[bk2 * 68 + bc2 + 1] = b1;
            sB[bk2 * 68 + bc2 + 2] = b2; sB[bk2 * 68 + bc2 + 3] = b3;
            __syncthreads();
            if (k0 + 16 < C_) {
                const double* ap = aptr + k0 + 16;
                a0 = ap[0]; a1 = ap[1]; a2 = ap[2]; a3 = ap[3];
                const double* bp = bptr + (size_t)(k0 + 16) * C3_;
                b0 = bp[0]; b1 = bp[1]; b2 = bp[2]; b3 = bp[3];
            }
#pragma unroll
            for (int ks = 0; ks < 4; ++ks) {
                double av0 = sA[(wr * 32 + ar_f) * 17 + ks * 4 + ak_f];
                double av1 = sA[(wr * 32 + 16 + ar_f) * 17 + ks * 4 + ak_f];
                double bv0 = sB[(ks * 4 + bk_f) * 68 + wc * 32 + bc_f];
                double bv1 = sB[(ks * 4 + bk_f) * 68 + wc * 32 + 16 + bc_f];
                acc[0][0] = __builtin_amdgcn_mfma_f64_16x16x4f64(av0, bv0, acc[0][0], 0, 0, 0);
                acc[0][1] = __builtin_amdgcn_mfma_f64_16x16x4f64(av0, bv1, acc[0][1], 0, 0, 0);
                acc[1][0] = __builtin_amdgcn_mfma_f64_16x16x4f64(av1, bv0, acc[1][0], 0, 0, 0);
                acc[1][1] = __builtin_amdgcn_mfma_f64_16x16x4f64(av1, bv1, acc[1][1], 0, 0, 0);
            }
        }
        __syncthreads();
        if (tid < 64) s2buf[tid] = 0.0;
        __syncthreads();
#pragma unroll
        for (int fi = 0; fi < 2; ++fi) {
#pragma unroll
            for (int d = 0; d < 4; ++d) {
                int localr = wr * 32 + fi * 16 + drr[d];
                int row = row0 + localr;
                int b = row / N_, nn = row - b * N_;
                double p = pol[row];
                double s2 = 0.0;
#pragma unroll
                for (int fj = 0; fj < 2; ++fj) {
                    int c = wc * 32 + fj * 16 + dcc[d];
                    double vv = acc[fi][fj][d] * p;
                    v32[(((size_t)(b * H_ + bx)) * N_ + nn) * HD_ + c] = (float)vv;
                    s2 += vv * vv;
                }
                atomicAdd(&s2buf[localr], s2);
            }
        }
        __syncthreads();
        if (tid < 64) atomicAdd(&vnorm2[row0 + tid], s2buf[tid]);
    } else {
        // ---------- VALU fallback ----------
        double (*As)[65] = (double (*)[65])sA;
        double (*Bs)[68] = (double (*)[68])sB;
        const int tx = tid & 15, ty = tid >> 4;
        const int arow = tid & 63, ak = (tid >> 6) * 4;
        const int brow = tid >> 4, bcol = (tid & 15) * 4;

        double acc[4][4];
#pragma unroll
        for (int i = 0; i < 4; ++i)
#pragma unroll
            for (int j = 0; j < 4; ++j) acc[i][j] = 0.0;

        const int gr = row0 + arow;
        for (int k0 = 0; k0 < C_; k0 += 16) {
            const double* ap = A + (size_t)gr * C_ + k0 + ak;
            double a0 = ap[0], a1 = ap[1], a2 = ap[2], a3 = ap[3];
            const double* bp = W + (size_t)(k0 + brow) * C3_ + 2 * C_ + col0 + bcol;
            double b0 = bp[0], b1 = bp[1], b2 = bp[2], b3 = bp[3];
            __syncthreads();
            As[ak + 0][arow] = a0; As[ak + 1][arow] = a1; As[ak + 2][arow] = a2; As[ak + 3][arow] = a3;
            Bs[brow][bcol + 0] = b0; Bs[brow][bcol + 1] = b1; Bs[brow][bcol + 2] = b2; Bs[brow][bcol + 3] = b3;
            __syncthreads();
#pragma unroll
            for (int kk = 0; kk < 16; ++kk) {
                double aa[4], bb[4];
#pragma unroll
                for (int i = 0; i < 4; ++i) aa[i] = As[kk][ty * 4 + i];
#pragma unroll
                for (int j = 0; j < 4; ++j) bb[j] = Bs[kk][tx + 16 * j];
#pragma unroll
                for (int i = 0; i < 4; ++i)
#pragma unroll
                    for (int j = 0; j < 4; ++j) acc[i][j] += aa[i] * bb[j];
            }
        }
#pragma unroll
        for (int i = 0; i < 4; ++i) {
            int row = row0 + ty * 4 + i;
            int b = row / N_, nn = row - b * N_;
            double p = pol[row];
            double s2 = 0.0;
#pragma unroll
            for (int j = 0; j < 4; ++j) {
                double vv = acc[i][j] * p;
                v32[(((size_t)(b * H_ + bx)) * N_ + nn) * HD_ + tx + 16 * j] = (float)vv;
                s2 += vv * vv;
            }
            s2 += __shfl_xor(s2, 1, 64);
            s2 += __shfl_xor(s2, 2, 64);
            s2 += __shfl_xor(s2, 4, 64);
            s2 += __shfl_xor(s2, 8, 64);
            if (tx == 0) atomicAdd(&vnorm2[row], s2);
        }
    }
}

// ---------------- MFMA split-bf16 GEMM: 128x128 tile, K-step 32 ----------------
struct Epi {
    const float* bias;
    const int* srctok;
    const void* xin;
    float* x2out;
    bf16* act;
    const float* x2in;
    void* dout;
    const int* flagp;
    float* qq; float* kk;
    const double* pol;
};

// MODE: 0 = qk scatter, 1 = proj -> x2, 2 = fc1 gelu -> act bf16, 3 = fc2 -> out
template <int MODE, bool SPLITA>
__global__ __launch_bounds__(256) void mgemm(const ushort_t* __restrict__ Ah,
                                             const ushort_t* __restrict__ Al,
                                             const ushort_t* __restrict__ Bh,
                                             const ushort_t* __restrict__ Bl,
                                             int M, int K, int NBX, Epi ep) {
    __shared__ ushort_t As_h[4096];
    __shared__ ushort_t As_l[4096];
    __shared__ ushort_t Bs_h[4096];
    __shared__ ushort_t Bs_l[4096];
    const int tid = threadIdx.x;
    const int lane = tid & 63, w = tid >> 6;
    const int wr = w >> 1, wc = w & 1;
    const int quad = lane >> 4, mn = lane & 15;
    int bx, by;
    xcd_decode(blockIdx.x, NBX * 99, NBX, bx, by);
    const int row0 = by * 128, col0 = bx * 128;

    floatx4 acc[4][4];
#pragma unroll
    for (int i = 0; i < 4; ++i)
#pragma unroll
        for (int j = 0; j < 4; ++j) acc[i][j] = floatx4{0.f, 0.f, 0.f, 0.f};

    const int srow = tid >> 2, soct = tid & 3;       // s=0 chunk
    const int srow2 = (tid + 256) >> 2;              // s=1 chunk (oct same)
    const int dst1 = (((srow >> 4) * 4 + soct) * 16 + (srow & 15)) * 8;
    const int dst2 = (((srow2 >> 4) * 4 + soct) * 16 + (srow2 & 15)) * 8;

    for (int k0 = 0; k0 < K; k0 += 32) {
        uint4 ah1, ah2, al1, al2, bh1, bh2, bl1, bl2;
        const uint4 zz = make_uint4(0, 0, 0, 0);
        {
            int gr = row0 + srow;
            size_t go = (size_t)gr * K + k0 + soct * 8;
            if (gr < M) { ah1 = *(const uint4*)(Ah + go); al1 = SPLITA ? *(const uint4*)(Al + go) : zz; }
            else        { ah1 = zz; al1 = zz; }
            gr = row0 + srow2;
            go = (size_t)gr * K + k0 + soct * 8;
            if (gr < M) { ah2 = *(const uint4*)(Ah + go); al2 = SPLITA ? *(const uint4*)(Al + go) : zz; }
            else        { ah2 = zz; al2 = zz; }
            size_t bo = (size_t)(col0 + srow) * K + k0 + soct * 8;
            bh1 = *(const uint4*)(Bh + bo); bl1 = *(const uint4*)(Bl + bo);
            bo = (size_t)(col0 + srow2) * K + k0 + soct * 8;
            bh2 = *(const uint4*)(Bh + bo); bl2 = *(const uint4*)(Bl + bo);
        }
        __syncthreads();
        *(uint4*)(As_h + dst1) = ah1; *(uint4*)(As_h + dst2) = ah2;
        if (SPLITA) { *(uint4*)(As_l + dst1) = al1; *(uint4*)(As_l + dst2) = al2; }
        *(uint4*)(Bs_h + dst1) = bh1; *(uint4*)(Bs_h + dst2) = bh2;
        *(uint4*)(Bs_l + dst1) = bl1; *(uint4*)(Bs_l + dst2) = bl2;
        __syncthreads();

        short8 afh[4], afl[4], bfh[4], bfl[4];
#pragma unroll
        for (int i = 0; i < 4; ++i) {
            int off = ((wr * 4 + i) * 64 + lane) * 8;
            afh[i] = *(const short8*)(As_h + off);
            if (SPLITA) afl[i] = *(const short8*)(As_l + off);
        }
#pragma unroll
        for (int j = 0; j < 4; ++j) {
            int off = ((wc * 4 + j) * 64 + lane) * 8;
            bfh[j] = *(const short8*)(Bs_h + off);
            bfl[j] = *(const short8*)(Bs_l + off);
        }
#pragma unroll
        for (int i = 0; i < 4; ++i)
#pragma unroll
            for (int j = 0; j < 4; ++j) {
                acc[i][j] = __builtin_amdgcn_mfma_f32_16x16x32_bf16(afh[i], bfh[j], acc[i][j], 0, 0, 0);
                acc[i][j] = __builtin_amdgcn_mfma_f32_16x16x32_bf16(afh[i], bfl[j], acc[i][j], 0, 0, 0);
                if (SPLITA)
                    acc[i][j] = __builtin_amdgcn_mfma_f32_16x16x32_bf16(afl[i], bfh[j], acc[i][j], 0, 0, 0);
            }
    }

    // epilogue: element (i,j,r): row = row0+wr*64+i*16+quad*4+r, col = col0+wc*64+j*16+mn
    if constexpr (MODE == 0) {
#pragma unroll
        for (int j = 0; j < 4; ++j) {
            int col = col0 + wc * 64 + j * 16 + mn;
            int comp = (col >= C_) ? 1 : 0;
            int rem = col - comp * C_;
            int hh = rem >> 6, d0 = rem & 63;
            float* dstbase = comp ? ep.kk : ep.qq;
#pragma unroll
            for (int i = 0; i < 4; ++i) {
                int rbase = row0 + wr * 64 + i * 16 + quad * 4;
#pragma unroll
                for (int r = 0; r < 4; ++r) {
                    int row = rbase + r; if (row >= M) continue;
                    int b = row / N_, nn = row - b * N_;
                    float pv = (float)ep.pol[row];
                    dstbase[(((size_t)(b * H_ + hh)) * N_ + nn) * HD_ + d0] = acc[i][j][r] * pv;
                }
            }
        }
    } else if constexpr (MODE == 1) {
        const bool f32 = (*ep.flagp != 0);
#pragma unroll
        for (int i = 0; i < 4; ++i) {
            int rbase = row0 + wr * 64 + i * 16 + quad * 4;
#pragma unroll
            for (int r = 0; r < 4; ++r) {
                int row = rbase + r; if (row >= M) continue;
                int st = ep.srctok[row];
                float polv = (st >= 0) ? 1.f : 0.f;
                int b = row / N_;
                size_t xrow = ((size_t)(b * N_ + (st < 0 ? 0 : st))) * C_;
#pragma unroll
                for (int j = 0; j < 4; ++j) {
                    int col = col0 + wc * 64 + j * 16 + mn;
                    float selx = (st >= 0) ? load_in(ep.xin, xrow + col, f32) : 0.f;
                    ep.x2out[(size_t)row * C_ + col] = selx + (acc[i][j][r] + ep.bias[col]) * polv;
                }
            }
        }
    } else if constexpr (MODE == 2) {
#pragma unroll
        for (int i = 0; i < 4; ++i) {
            int rbase = row0 + wr * 64 + i * 16 + quad * 4;
#pragma unroll
            for (int r = 0; r < 4; ++r) {
                int row = rbase + r; if (row >= M) continue;
#pragma unroll
                for (int j = 0; j < 4; ++j) {
                    int col = col0 + wc * 64 + j * 16 + mn;
                    float z = acc[i][j][r] + ep.bias[col];
                    float gl = 0.5f * z * (1.0f + erff(z * 0.70710678118654752f));
                    ep.act[(size_t)row * C4_ + col] = f2bf(gl);
                }
            }
        }
    } else {
        const bool f32out = (*ep.flagp != 0);
#pragma unroll
        for (int i = 0; i < 4; ++i) {
            int rbase = row0 + wr * 64 + i * 16 + quad * 4;
#pragma unroll
            for (int r = 0; r < 4; ++r) {
                int row = rbase + r; if (row >= M) continue;
                int st = ep.srctok[row];
                float polv = (st >= 0) ? 1.f : 0.f;
#pragma unroll
                for (int j = 0; j < 4; ++j) {
                    int col = col0 + wc * 64 + j * 16 + mn;
                    float val = (ep.x2in[(size_t)row * C_ + col] + acc[i][j][r] + ep.bias[col]) * polv;
                    size_t o = (size_t)row * C_ + col;
                    if (f32out) ((float*)ep.dout)[o] = val;
                    else        ((bf16*)ep.dout)[o] = f2bf(val);
                }
            }
        }
    }
}

// ---------------- attention probs (row stride KP_, zero-padded tail) ----------------
__global__ __launch_bounds__(256) void attn_kernel(const float* __restrict__ q,
                                                   const float* __restrict__ k,
                                                   const double* __restrict__ policy,
                                                   bf16* __restrict__ attn) {
    __shared__ float Ks[197 * 69];
    __shared__ float ps[256];
    const int bh = blockIdx.x, b = bh / H_;
    const int tid = threadIdx.x;
    const float* kbase = k + (size_t)bh * N_ * HD_;
    for (int idx = tid; idx < N_ * HD_; idx += 256) Ks[(idx >> 6) * 69 + (idx & 63)] = kbase[idx];
    for (int j = tid; j < 256; j += 256) ps[j] = (j < N_) ? (float)policy[b * N_ + j] : 0.f;
    __syncthreads();
    const int w = tid >> 6, lane = tid & 63;
    const int j0 = lane, j1 = lane + 64, j2 = lane + 128, j3 = lane + 192;
    const bool h3 = (lane < 5);
    const float* k0p = &Ks[j0 * 69];
    const float* k1p = &Ks[j1 * 69];
    const float* k2p = &Ks[j2 * 69];
    const float* k3p = h3 ? &Ks[j3 * 69] : &Ks[j0 * 69];
    const float p0 = ps[j0], p1 = ps[j1], p2 = ps[j2], p3 = h3 ? ps[j3] : 0.f;
    const float* qbase = q + (size_t)bh * N_ * HD_;
    for (int i = w; i < N_; i += 4) {
        const float* qr = qbase + i * HD_;
        float a0 = 0.f, a1 = 0.f, a2 = 0.f, a3 = 0.f;
#pragma unroll 8
        for (int d = 0; d < 64; ++d) {
            float qd = qr[d];
            a0 += qd * k0p[d]; a1 += qd * k1p[d]; a2 += qd * k2p[d]; a3 += qd * k3p[d];
        }
        float s0 = a0 * 0.125f, s1 = a1 * 0.125f, s2 = a2 * 0.125f;
        float s3 = h3 ? a3 * 0.125f : -INFINITY;
        float m = fmaxf(fmaxf(s0, s2), fmaxf(s1, s3));
        for (int off = 32; off > 0; off >>= 1) m = fmaxf(m, __shfl_down(m, off, 64));
        float mx = __shfl(m, 0, 64);
        float e0 = expf(s0 - mx) * (p0 + (1.f - p0) * ((j0 == i) ? 1.f : 0.f));
        float e1 = expf(s1 - mx) * (p1 + (1.f - p1) * ((j1 == i) ? 1.f : 0.f));
        float e2 = expf(s2 - mx) * (p2 + (1.f - p2) * ((j2 == i) ? 1.f : 0.f));
        float e3 = h3 ? expf(s3 - mx) * (p3 + (1.f - p3) * ((j3 == i) ? 1.f : 0.f)) : 0.f;
        float su = (e0 + e2) + (e1 + e3);
        for (int off = 32; off > 0; off >>= 1) su += __shfl_down(su, off, 64);
        float ssum = __shfl(su, 0, 64);
        bf16* orow = attn + ((size_t)bh * N_ + i) * KP_;
        orow[j0] = f2bf((e0 + 5.0761421319796954e-9f) / (ssum + 1e-6f));
        orow[j1] = f2bf((e1 + 5.0761421319796954e-9f) / (ssum + 1e-6f));
        orow[j2] = f2bf((e2 + 5.0761421319796954e-9f) / (ssum + 1e-6f));
        if (h3)               orow[j3] = f2bf((e3 + 5.0761421319796954e-9f) / (ssum + 1e-6f));
        else if (j3 < KP_)    orow[j3] = f2bf(0.f);   // zero pad cols 197..223
    }
}

// ---------------- fused score + sampling (decision path; score arithmetic verbatim) ----------------
DEV void bitonic_fi64(double* key, int* idx) {
    const int tid = threadIdx.x;
    for (int ksz = 2; ksz <= 256; ksz <<= 1)
        for (int jj = ksz >> 1; jj > 0; jj >>= 1) {
            __syncthreads();
            int ixj = tid ^ jj;
            if (ixj > tid) {
                double ka = key[tid], kb = key[ixj];
                int ia = idx[tid], ib = idx[ixj];
                bool up = (tid & ksz) == 0;
                bool agtb = (ka > kb) || (ka == kb && ia > ib);
                if (agtb == up) { key[tid] = kb; key[ixj] = ka; idx[tid] = ib; idx[ixj] = ia; }
            }
        }
    __syncthreads();
}
DEV void bitonic_int(int* a) {
    const int tid = threadIdx.x;
    for (int ksz = 2; ksz <= 256; ksz <<= 1)
        for (int jj = ksz >> 1; jj > 0; jj >>= 1) {
            __syncthreads();
            int ixj = tid ^ jj;
            if (ixj > tid) {
                int va = a[tid], vb = a[ixj];
                bool up = (tid & ksz) == 0;
                if ((va > vb) == up) { a[tid] = vb; a[ixj] = va; }
            }
        }
    __syncthreads();
}

__global__ __launch_bounds__(256) void sample_kernel(const double* __restrict__ cls,
                                                     const double* __restrict__ vnorm2,
                                                     int* __restrict__ srctok) {
    __shared__ double key[256];
    __shared__ int   idx[256];
    __shared__ double ncdf[196];
    __shared__ double red[256];
    __shared__ double sraw[256];
    __shared__ int   s1[256];
    __shared__ int   s2[256];
    __shared__ double cmm[2];
    const int b = blockIdx.x, tid = threadIdx.x;

    // --- score phase (identical arithmetic to old score_kernel) ---
    {
        const int t = tid;
        double raw = 0.0;
        if (t < N_) {
            double cs = 0.0;
            for (int h = 0; h < H_; ++h) cs += cls[(size_t)(b * H_ + h) * N_ + t];
            raw = cs * sqrt(vnorm2[b * N_ + t]);
        }
        double contrib = (t >= 1 && t < N_) ? raw : 0.0;
        double tot = bred_sum64(contrib, red);
        sraw[t] = raw;
        __syncthreads();
        key[tid] = (tid < NM1) ? (sraw[tid + 1] / tot) : INFINITY;
    }
    idx[tid] = tid;
    __syncthreads();
    bitonic_fi64(key, idx);

    if (tid == 0) {
        double c = 0.0, mn = INFINITY, mx = -INFINITY;
        for (int j = 0; j < NM1; ++j) {
            c += key[j]; ncdf[j] = c;
            mn = fmin(mn, c); mx = fmax(mx, c);
        }
        cmm[0] = mn; cmm[1] = mx;
    }
    __syncthreads();
    double cmin = cmm[0], cmax = cmm[1];
    if (tid < NM1) ncdf[tid] = (ncdf[tid] - cmin) / (cmax - cmin);
    __syncthreads();

    double vsm = (tid < NM1) ? (ncdf[tid] + ((ncdf[tid] == 0.0) ? 1e8 : 0.0)) : INFINITY;
    double ys_start = bred_min64(vsm, red);

    int tp = 0x7fffffff;
    if (tid < NM1) {
        double yj = (tid == 195) ? 1.0 : (double)tid * (1.0 / 195.0);
        double ys = ys_start + (yj * 195.0 - ys_start * (double)tid) / 195.0;
        double best = fabs(ys - ncdf[0]); int bj = 0;
        for (int j = 1; j < NM1; ++j) {
            double d = fabs(ys - ncdf[j]);
            if (d < best) { best = d; bj = j; }
        }
        tp = bj;
    }
    s1[tid] = tp; __syncthreads();
    bitonic_int(s1);

    int u = 0x7fffffff;
    if (tid < NM1) {
        int sv = s1[tid];
        int nxt = (tid < NM1 - 1) ? s1[tid + 1] : 1;
        u = (nxt == sv) ? NM1 : sv;
    }
    __syncthreads();
    s2[tid] = u; __syncthreads();
    bitonic_int(s2);

    if (tid < N_) {
        int st;
        if (tid == 0) st = 0;
        else {
            int uu = s2[tid - 1];
            st = (uu == NM1) ? -1 : (1 + idx[uu]);
        }
        srctok[(size_t)b * N_ + tid] = st;
    }
}

// ---------------- xo = gathered_attn @ v via bf16 MFMA, split output ----------------
__global__ __launch_bounds__(256) void av_mfma(const bf16* __restrict__ attn,
                                               const float* __restrict__ v,
                                               const int* __restrict__ srctok,
                                               ushort_t* __restrict__ xoh,
                                               ushort_t* __restrict__ xol) {
    __shared__ ushort_t Bsh[4 * 7 * 4 * 16 * 8];   // 14336
    __shared__ ushort_t Bsl[4 * 7 * 4 * 16 * 8];
    const int bh = blockIdx.x, b = bh / H_, hd = bh - b * H_;
    const int tid = threadIdx.x, lane = tid & 63, w = tid >> 6;
    const int mn = lane & 15, oct = lane >> 4;

#pragma unroll
    for (int cf = 0; cf < 4; ++cf) {
        int base = (cf * 7 + 6) * 512;
        for (int o = tid; o < 512; o += 256) { Bsh[base + o] = 0; Bsl[base + o] = 0; }
    }
    __syncthreads();
    const float* vb = v + (size_t)bh * (N_ * HD_);
    for (int idx = tid; idx < N_ * HD_; idx += 256) {
        int m = idx >> 6, d = idx & 63;
        ushort_t h, l; split_bf(vb[idx], h, l);
        int o = ((((d >> 4) * 7 + (m >> 5)) * 4 + ((m >> 3) & 3)) * 16 + (d & 15)) * 8 + (m & 7);
        Bsh[o] = h; Bsl[o] = l;
    }
    __syncthreads();

    const int nf = (w == 0) ? 4 : 3;
    const int frg[4] = { w, w + 4, w + 8, 12 };

    floatx4 acc[4][4];
#pragma unroll
    for (int f = 0; f < 4; ++f)
#pragma unroll
        for (int cf = 0; cf < 4; ++cf) acc[f][cf] = floatx4{0.f, 0.f, 0.f, 0.f};

    size_t abase[4]; bool aval[4];
#pragma unroll
    for (int f = 0; f < 4; ++f) {
        int row = frg[f] * 16 + mn;
        int st = (f < nf && row < N_) ? srctok[b * N_ + row] : -1;
        aval[f] = (st >= 0);
        abase[f] = ((size_t)bh * N_ + (st < 0 ? 0 : st)) * KP_ + oct * 8;
    }

    const short8 z8 = short8{0, 0, 0, 0, 0, 0, 0, 0};
    const ushort_t* ap = (const ushort_t*)attn;
    for (int ks = 0; ks < 7; ++ks) {
        const int k0 = ks * 32;
        short8 af[4];
#pragma unroll
        for (int f = 0; f < 4; ++f)
            af[f] = aval[f] ? *(const short8*)(ap + abase[f] + k0) : z8;
#pragma unroll
        for (int cf = 0; cf < 4; ++cf) {
            int bo = (((cf * 7 + ks) * 4 + oct) * 16 + mn) * 8;
            short8 bh8 = *(const short8*)(Bsh + bo);
            short8 bl8 = *(const short8*)(Bsl + bo);
#pragma unroll
            for (int f = 0; f < 4; ++f) {
                if (f < nf) {
                    acc[f][cf] = __builtin_amdgcn_mfma_f32_16x16x32_bf16(af[f], bh8, acc[f][cf], 0, 0, 0);
                    acc[f][cf] = __builtin_amdgcn_mfma_f32_16x16x32_bf16(af[f], bl8, acc[f][cf], 0, 0, 0);
                }
            }
        }
    }

    const int quad = lane >> 4;
#pragma unroll
    for (int f = 0; f < 4; ++f) {
        if (f >= nf) continue;
#pragma unroll
        for (int r = 0; r < 4; ++r) {
            int row = frg[f] * 16 + quad * 4 + r;
            if (row >= N_) continue;
            size_t ob = ((size_t)(b * N_) + row) * C_ + hd * 64;
#pragma unroll
            for (int cf = 0; cf < 4; ++cf) {
                ushort_t h, l; split_bf(acc[f][cf][r], h, l);
                xoh[ob + cf * 16 + mn] = h;
                xol[ob + cf * 16 + mn] = l;
            }
        }
    }
}

// ---------------- launch ----------------
extern "C" void kernel_launch(void* const* d_in, const int* in_sizes, int n_in,
                              void* d_out, int out_size, void* d_ws, size_t ws_size,
                              hipStream_t stream) {
    char* ws = (char*)d_ws;
    int*      flag     = (int*)     (ws + 0);
    int*      mfmamode = (int*)     (ws + 64);
    double*   w64      = (double*)  (ws + 256);          // 14,155,776
    ushort_t* wqkvT_h  = (ushort_t*)(ws + 14156032);     //  2,359,296
    ushort_t* wqkvT_l  = (ushort_t*)(ws + 16515328);     //  2,359,296
    ushort_t* wprojT_h = (ushort_t*)(ws + 18874624);     //  1,179,648
    ushort_t* wprojT_l = (ushort_t*)(ws + 20054272);     //  1,179,648
    ushort_t* wfc1T_h  = (ushort_t*)(ws + 21233920);     //  4,718,592
    ushort_t* wfc1T_l  = (ushort_t*)(ws + 25952512);     //  4,718,592
    ushort_t* wfc2T_h  = (ushort_t*)(ws + 30671104);     //  4,718,592
    ushort_t* wfc2T_l  = (ushort_t*)(ws + 35389696);     //  4,718,592
    double*   pol64    = (double*)  (ws + 40108288);     //    100,864
    double*   g1_64    = (double*)  (ws + 40209152);     //      6,144
    double*   b1_64    = (double*)  (ws + 40215296);     //      6,144
    float*    g2_32    = (float*)   (ws + 40221440);     //      3,072
    float*    b2_32    = (float*)   (ws + 40224512);     //      3,072
    float*    bproj32  = (float*)   (ws + 40227584);     //      3,072
    float*    bfc1_32  = (float*)   (ws + 40230656);     //     12,288
    float*    bfc2_32  = (float*)   (ws + 40242944);     //      3,072
    double*   q0_64    = (double*)  (ws + 40246016);     //    393,216
    double*   wq0_64   = (double*)  (ws + 40639232);     //  4,718,592
    double*   vnorm2   = (double*)  (ws + 45357824);     //    100,864
    double*   cls64    = (double*)  (ws + 45458688);     //  1,210,368
    double*   score64  = (double*)  (ws + 46669056);     //    100,352 (unused, kept for layout)
    int*      srctok   = (int*)     (ws + 46769408);     //     50,432
    // big slots (lifetime-sequenced):
    double*   xn64     = (double*)  (ws + 48000000);     // 77,463,552
    bf16*     attn     = (bf16*)    (ws + 48000000);     // 67,768,320
    bf16*     act      = (bf16*)    (ws + 48000000);     // 77,463,552
    ushort_t* xn_h     = (ushort_t*)(ws + 125463552);    // 19,365,888
    ushort_t* xn_l     = (ushort_t*)(ws + 144829440);    // 19,365,888
    float*    v32      = (float*)   (ws + 125463552);    // 38,731,776
    float*    q32      = (float*)   (ws + 164195328);    // 38,731,776
    ushort_t* xo_h     = (ushort_t*)(ws + 164195328);    // 19,365,888
    ushort_t* xo_l     = (ushort_t*)(ws + 183561216);    // 19,365,888
    ushort_t* h1_h     = (ushort_t*)(ws + 164195328);    // 19,365,888
    ushort_t* h1_l     = (ushort_t*)(ws + 183561216);    // 19,365,888
    float*    k32      = (float*)   (ws + 202927104);    // 38,731,776
    float*    x2_32    = (float*)   (ws + 202927104);    // 38,731,776
    (void)score64;

    const dim3 blk(256);

    // 0) dtype detect + fused conversions/probe + weight transposes
    detect_kernel<<<1, blk, 0, stream>>>((const ushort_t*)d_in[2], flag);
    { PrepArgs a;
      a.bproj_s = d_in[4]; a.g1_s = d_in[5]; a.b1_s = d_in[6]; a.g2_s = d_in[7];
      a.b2_s = d_in[8]; a.bfc1_s = d_in[10]; a.bfc2_s = d_in[12]; a.pol_s = d_in[1];
      a.bproj_d = bproj32; a.g2_d = g2_32; a.b2_d = b2_32; a.bfc1_d = bfc1_32; a.bfc2_d = bfc2_32;
      a.g1_d = g1_64; a.b1_d = b1_64; a.pol_d = pol64; a.vn_d = vnorm2;
      a.mode = mfmamode; a.flag = flag;
      prep_small<<<131, blk, 0, stream>>>(a); }
    cvt64_kernel<<<1024, blk, 0, stream>>>(d_in[2], w64, C_ * C3_, flag);
    { TSArgs a;
      a.w0 = d_in[2];  a.h0 = wqkvT_h;  a.l0 = wqkvT_l;
      a.w1 = d_in[3];  a.h1 = wprojT_h; a.l1 = wprojT_l;
      a.w2 = d_in[9];  a.h2 = wfc1T_h;  a.l2 = wfc1T_l;
      a.w3 = d_in[11]; a.h3 = wfc2T_h;  a.l3 = wfc2T_l;
      a.flag = flag;
      tsplit_all<<<6336, blk, 0, stream>>>(a); }

    // 1) LN1 fp64 (+ split copy)
    ln64_kernel<<<M_, blk, 0, stream>>>(d_in[0], g1_64, b1_64, xn64, xn_h, xn_l, flag);

    // 2) fp64 score-path precursors (parallelized grids)
    q0_kernel<<<dim3(B_, 3), blk, 0, stream>>>(xn64, w64, pol64, q0_64);
    wq0_kernel<<<dim3(B_, 3), blk, 0, stream>>>(w64, q0_64, wq0_64);

    // 3) q,k via split-bf16 MFMA GEMM (split A restored — r14 showed hi-only
    //    gains nothing here; keep the extra precision margin for free)
    { Epi e = {}; e.qq = q32; e.kk = k32; e.pol = pol64;
      mgemm<0, true><<<12 * 99, blk, 0, stream>>>(xn_h, xn_l, wqkvT_h, wqkvT_l, M_, C_, 12, e); }

    // 4) v fp64 GEMM v2 (decision path, 64x64 tile, XCD-swizzled) -> v32 + vnorm2
    gemm64v2<<<12 * 197, blk, 0, stream>>>(xn64, w64, pol64, v32, vnorm2, mfmamode);

    // 5) cls rows fp64 (ph split across blockIdx.y; last use of xn64)
    cls_kernel<<<dim3(B_, 2), blk, 0, stream>>>(xn64, wq0_64, pol64, cls64);

    // 6) attention probs (writes SL1 over dead xn64, stride KP_)
    attn_kernel<<<BH_, blk, 0, stream>>>(q32, k32, pol64, attn);

    // 7) fused score + sampling
    sample_kernel<<<B_, blk, 0, stream>>>(cls64, vnorm2, srctok);

    // 8) xo = gathered attn @ v via MFMA -> split (SL3 over dead q32)
    av_mfma<<<BH_, blk, 0, stream>>>(attn, v32, srctok, xo_h, xo_l);

    // 9) proj MFMA -> x2 (A = xo hi-only; measured win, absmax unchanged)
    { Epi e = {}; e.bias = bproj32; e.srctok = srctok; e.xin = d_in[0]; e.x2out = x2_32; e.flagp = flag;
      mgemm<1, false><<<6 * 99, blk, 0, stream>>>(xo_h, xo_l, wprojT_h, wprojT_l, M_, C_, 6, e); }

    // 10) LN2 fp32 -> h1 split (SL3 over dead xo)
    ln32_kernel<<<M_, blk, 0, stream>>>(x2_32, g2_32, b2_32, h1_h, h1_l);

    // 11) fc1 MFMA + GELU -> act bf16 (A = h1 hi-only; measured win, absmax unchanged)
    { Epi e = {}; e.bias = bfc1_32; e.act = act;
      mgemm<2, false><<<24 * 99, blk, 0, stream>>>(h1_h, h1_l, wfc1T_h, wfc1T_l, M_, C_, 24, e); }

    // 12) fc2 MFMA (bf16 act as A-hi) + residual + pol -> out
    { Epi e = {}; e.bias = bfc2_32; e.srctok = srctok; e.x2in = x2_32; e.dout = d_out; e.flagp = flag;
      mgemm<3, false><<<6 * 99, blk, 0, stream>>>((const ushort_t*)act, nullptr, wfc2T_h, wfc2T_l, M_, C4_, 6, e); }
}